// Round 13
// baseline (373.851 us; speedup 1.0000x reference)
//
#include <hip/hip_runtime.h>
#include <math.h>

#define B_ 8
#define C_ 256
#define S_ 1024
#define N_ 512
#define KV_ 512
#define REL_ 64
#define NH_ 8
#define DH_ 64
#define KSEL_ 307
#define NBLK_ 512

typedef __attribute__((ext_vector_type(8))) short bf16x8;
typedef __attribute__((ext_vector_type(4))) short short4v;
typedef __attribute__((ext_vector_type(4))) float f32x4;

__device__ __forceinline__ short f2bf(float f) {
  unsigned int u = __float_as_uint(f);
  u += 0x7fffu + ((u >> 16) & 1u);
  return (short)(u >> 16);
}

// device-scope grid barrier (all NBLK_ blocks co-resident by construction; counter zeroed per launch)
__device__ __forceinline__ void grid_barrier(int* bar, int target) {
  __syncthreads();
  if (threadIdx.x == 0) {
    __hip_atomic_fetch_add(bar, 1, __ATOMIC_RELEASE, __HIP_MEMORY_SCOPE_AGENT);
    while (__hip_atomic_load(bar, __ATOMIC_ACQUIRE, __HIP_MEMORY_SCOPE_AGENT) < target)
      __builtin_amdgcn_s_sleep(2);
  }
  __syncthreads();
}

// ==================== L1: converts + h-transpose + rel-proj (split-K x8) ====================
__global__ __launch_bounds__(256) void k_prep(const float* __restrict__ cond, const float* __restrict__ Wq,
                                              const float* __restrict__ Wk, const float* __restrict__ Wv,
                                              const float* __restrict__ Wo, const float* __restrict__ h,
                                              const float* __restrict__ Wrk,
                                              short* __restrict__ cond_b, short* __restrict__ Wq_b,
                                              short* __restrict__ Wk_b, short* __restrict__ Wv_b,
                                              short* __restrict__ Wo_b, short* __restrict__ hT,
                                              float* __restrict__ cp_part) {
  __shared__ float fs[2176];
  int blk = blockIdx.x, tid = threadIdx.x;
  if (blk < 2816) {
    const float* src; short* dst; int base;
    if (blk < 2048)      { src = cond; dst = cond_b; base = blk; }
    else if (blk < 2176) { src = Wq;   dst = Wq_b;   base = blk - 2048; }
    else if (blk < 2432) { src = Wk;   dst = Wk_b;   base = blk - 2176; }
    else if (blk < 2688) { src = Wv;   dst = Wv_b;   base = blk - 2432; }
    else                 { src = Wo;   dst = Wo_b;   base = blk - 2688; }
    int i = base * 256 + tid;
    float4 v = ((const float4*)src)[i];
    short4v o = { f2bf(v.x), f2bf(v.y), f2bf(v.z), f2bf(v.w) };
    ((short4v*)dst)[i] = o;
  } else if (blk < 4864) {
    int i = blk - 2816;
    int s0 = (i & 31) * 32, c0 = ((i >> 5) & 7) * 32, b = i >> 8;
    int x = tid & 31, y0 = tid >> 5;
    #pragma unroll
    for (int y = y0; y < 32; y += 8)
      fs[y * 33 + x] = h[((size_t)(b * C_ + c0 + y)) * S_ + s0 + x];
    __syncthreads();
    #pragma unroll
    for (int y = y0; y < 32; y += 8)
      hT[((size_t)(b * S_ + s0 + y)) * C_ + c0 + x] = f2bf(fs[x * 33 + y]);
  } else {
    int i = blk - 4864;             // 0..511
    int bm = (i & 63) * 64, kb = i >> 6;
    float* As = fs;
    float* Bs = fs + 1088;
    int tm = (tid >> 4) << 2, tn = (tid & 15) << 2;
    float acc[4][4] = {};
    for (int k0 = kb * 64; k0 < kb * 64 + 64; k0 += 16) {
      #pragma unroll
      for (int ii = 0; ii < 4; ++ii) {
        int idx = tid + ii * 256;
        int r = idx >> 4, k = idx & 15;
        As[r * 17 + k] = cond[(size_t)(bm + r) * KV_ + k0 + k];
        Bs[r * 17 + k] = Wrk[(size_t)r * KV_ + k0 + k];
      }
      __syncthreads();
      #pragma unroll
      for (int k = 0; k < 16; ++k) {
        float a[4], bb[4];
        #pragma unroll
        for (int x = 0; x < 4; ++x) { a[x] = As[(tm + x) * 17 + k]; bb[x] = Bs[(tn + x) * 17 + k]; }
        #pragma unroll
        for (int x = 0; x < 4; ++x)
          #pragma unroll
          for (int y = 0; y < 4; ++y)
            acc[x][y] += a[x] * bb[y];
      }
      __syncthreads();
    }
    #pragma unroll
    for (int x = 0; x < 4; ++x)
      #pragma unroll
      for (int y = 0; y < 4; ++y)
        cp_part[(size_t)kb * 262144 + (size_t)(bm + tm + x) * 64 + tn + y] = acc[x][y];
  }
}

// ==================== MFMA GEMM body (round-12, 3-buf counted-vmcnt) ====================
template<int MODE, int GA, int GB, int WM>
__device__ __forceinline__ void gemm_body(const short* __restrict__ A, const short* __restrict__ W,
                                          const float* __restrict__ bias, void* __restrict__ Cout,
                                          short* As, short* Bs, size_t bm, size_t bn, int Kd, int Nout,
                                          const int* __restrict__ gidx, int cntv) {
  constexpr int BMv = WM * 32;
  constexpr int NIA = BMv / 64;
  constexpr int OPS = NIA + 2;
  int tid = threadIdx.x;
  int lane = tid & 63, wid = tid >> 6;
  int wr = wid >> 1, wc = wid & 1;
  f32x4 acc[WM][4] = {};
  int srow = lane >> 2;
  int schunk = lane & 3;
  int steps = Kd >> 5;

  int rowA[NIA ? NIA : 1], rowB[2];
  #pragma unroll
  for (int i = 0; i < NIA; ++i) {
    int rt = wid * (WM * 8) + i * 16 + srow;
    rowA[i] = GA ? (((int)bm + rt < cntv) ? gidx[bm + rt] : 0) : (int)(bm + rt);
  }
  #pragma unroll
  for (int i = 0; i < 2; ++i) {
    int rt = wid * 32 + i * 16 + srow;
    rowB[i] = GB ? (((int)bn + rt < cntv) ? gidx[bn + rt] : 0) : (int)(bn + rt);
  }

  #define STAGE_G(t, buf)                                                                              \
    {                                                                                                  \
      int k0s = (t) * 32;                                                                              \
      _Pragma("unroll")                                                                                \
      for (int i = 0; i < NIA; ++i) {                                                                  \
        int rt = wid * (WM * 8) + i * 16 + srow;                                                       \
        int sc_ = (schunk ^ ((rt >> 1) & 3)) * 8;                                                      \
        const short* ga = A + (size_t)rowA[i] * Kd + k0s + sc_;                                        \
        __builtin_amdgcn_global_load_lds((const __attribute__((address_space(1))) void*)ga,            \
            (__attribute__((address_space(3))) void*)(As + (buf) * (BMv * 32) +                        \
                                                     (wid * (WM * 8) + i * 16) * 32),                  \
            16, 0, 0);                                                                                 \
      }                                                                                                \
      _Pragma("unroll")                                                                                \
      for (int i = 0; i < 2; ++i) {                                                                    \
        int rt = wid * 32 + i * 16 + srow;                                                             \
        int sc_ = (schunk ^ ((rt >> 1) & 3)) * 8;                                                      \
        const short* gb = W + (size_t)rowB[i] * Kd + k0s + sc_;                                        \
        __builtin_amdgcn_global_load_lds((const __attribute__((address_space(1))) void*)gb,            \
            (__attribute__((address_space(3))) void*)(Bs + (buf) * 4096 + (wid * 32 + i * 16) * 32),   \
            16, 0, 0);                                                                                 \
      }                                                                                                \
    }

  STAGE_G(0, 0);
  STAGE_G(1, 1);

  int cur = 0;
  for (int t = 0; t < steps; ++t) {
    if (t == steps - 1)
      asm volatile("s_waitcnt vmcnt(0)" ::: "memory");
    else
      asm volatile("s_waitcnt vmcnt(%0)" :: "n"(OPS) : "memory");
    __syncthreads();
    if (t + 2 < steps) {
      int nb = cur + 2; if (nb >= 3) nb -= 3;
      STAGE_G(t + 2, nb);
    }
    const short* Ac = As + cur * (BMv * 32);
    const short* Bc = Bs + cur * 4096;
    bf16x8 a[WM], b[4];
    #pragma unroll
    for (int m = 0; m < WM; ++m) {
      int rt = wr * (WM * 16) + m * 16 + (lane & 15);
      a[m] = *(const bf16x8*)(Ac + rt * 32 + (((lane >> 4) ^ ((rt >> 1) & 3)) * 8));
    }
    #pragma unroll
    for (int n = 0; n < 4; ++n) {
      int rt = wc * 64 + n * 16 + (lane & 15);
      b[n] = *(const bf16x8*)(Bc + rt * 32 + (((lane >> 4) ^ ((rt >> 1) & 3)) * 8));
    }
    __builtin_amdgcn_s_setprio(1);
    #pragma unroll
    for (int m = 0; m < WM; ++m)
      #pragma unroll
      for (int n = 0; n < 4; ++n)
        acc[m][n] = __builtin_amdgcn_mfma_f32_16x16x32_bf16(a[m], b[n], acc[m][n], 0, 0, 0);
    __builtin_amdgcn_s_setprio(0);
    cur = (cur == 2) ? 0 : cur + 1;
  }
  #undef STAGE_G

  int c0 = lane & 15, r0q = lane >> 4;
  #pragma unroll
  for (int n = 0; n < 4; ++n) {
    size_t col = bn + wc * 64 + n * 16 + c0;
    #pragma unroll
    for (int m = 0; m < WM; ++m) {
      #pragma unroll
      for (int j = 0; j < 4; ++j) {
        size_t row = bm + wr * (WM * 16) + m * 16 + r0q * 4 + j;
        if (MODE == 0) {
          ((short*)Cout)[row * Nout + col] = f2bf(acc[m][n][j] + bias[col]);
        } else if (MODE == 1) {
          ((float*)Cout)[((col >> 10) * C_ + row) * S_ + (col & (S_ - 1))] = acc[m][n][j] + bias[row];
        } else {
          ((short*)Cout)[row * Nout + col] = f2bf(acc[m][n][j] + bias[row]);
        }
      }
    }
  }
}

// stage 64x64 tile, 4 waves, layout LDS[r][c] = G[r][c ^ (r&7)] (128-B rows)
__device__ __forceinline__ void stage_tile64(const short* gRowBase, int gStride, short* ldsBase, int wid, int lane) {
  int sub = lane >> 3;
  int colE = ((lane & 7) ^ sub) * 8;
  #pragma unroll
  for (int i = 0; i < 2; ++i) {
    int r = wid * 16 + i * 8 + sub;
    const short* gp = gRowBase + (size_t)r * gStride + colE;
    __builtin_amdgcn_global_load_lds((const __attribute__((address_space(1))) void*)gp,
                                     (__attribute__((address_space(3))) void*)(ldsBase + wid * 1024 + i * 512),
                                     16, 0, 0);
  }
}

// ==================== L2: persistent mega kernel (normalize/select/proj/attn/outproj) ====================
#define QK2L 0.18033688f  // 0.125 * log2(e)
__global__ __launch_bounds__(256, 2) void k_mega(
    const float* __restrict__ cp_part, const float* __restrict__ brk, float* __restrict__ cp,
    const int* __restrict__ cond_mask, int* __restrict__ idxb, int* __restrict__ cnt,
    const short* __restrict__ hT, const short* __restrict__ cond_b,
    const short* __restrict__ Wq_b, const short* __restrict__ Wk_b, const short* __restrict__ Wv_b,
    const float* __restrict__ bq, const float* __restrict__ bk, const float* __restrict__ bv,
    short* __restrict__ qb, short* __restrict__ Kc, short* __restrict__ Vtc,
    short* __restrict__ attn_b, const short* __restrict__ Wo_b, const float* __restrict__ bo,
    float* __restrict__ out, int* __restrict__ bar) {
  __shared__ char smem_raw[49152];
  int bid = blockIdx.x, tid = threadIdx.x;

  // ---------- P1: normalize (reduce 8 partials + bias + L2-normalize), 2 rows/wave ----------
  {
    int wid = tid >> 6, d = tid & 63;
    #pragma unroll
    for (int i = 0; i < 2; ++i) {
      int row = (bid * 4 + wid) * 2 + i;   // 0..4095
      size_t off = (size_t)row * 64 + d;
      float x = brk[d];
      #pragma unroll
      for (int s = 0; s < 8; ++s) x += cp_part[(size_t)s * 262144 + off];
      float ss = x * x;
      #pragma unroll
      for (int o = 32; o; o >>= 1) ss += __shfl_xor(ss, o);
      cp[off] = x / fmaxf(sqrtf(ss), 1e-12f);
    }
  }
  grid_barrier(bar, NBLK_);

  // ---------- P2: centrality + top-k + mask + fallback + compaction (blocks 0..7, 256 thr) ----------
  if (bid < 8) {
    float* part = (float*)smem_raw;        // 4x64
    float* vsum = part + 256;              // 64
    float* sc   = vsum + 64;               // 512
    int*   wcnt = (int*)(sc + 512);        // 8
    int b = bid;
    int d = tid & 63, g = tid >> 6;
    float sacc = 0.f;
    for (int n = g * 128; n < g * 128 + 128; ++n)
      sacc += cp[((size_t)b * N_ + n) * 64 + d];
    part[g * 64 + d] = sacc;
    __syncthreads();
    if (tid < 64) vsum[tid] = part[tid] + part[64 + tid] + part[128 + tid] + part[192 + tid];
    __syncthreads();
    #pragma unroll
    for (int rr = 0; rr < 2; ++rr) {
      int n = tid + rr * 256;
      const float* x = cp + ((size_t)b * N_ + n) * 64;
      float dsum = 0.f, dself = 0.f;
      #pragma unroll
      for (int dd = 0; dd < 64; ++dd) {
        float xv = x[dd];
        dsum += xv * vsum[dd];
        dself += xv * xv;
      }
      sc[n] = dsum - dself;
    }
    __syncthreads();
    int sel[2], rank[2];
    #pragma unroll
    for (int rr = 0; rr < 2; ++rr) {
      int n = tid + rr * 256;
      float v = sc[n];
      int r = 0;
      for (int j = 0; j < N_; ++j) {
        float u = sc[j];
        r += (u > v) || (u == v && j < n);
      }
      rank[rr] = r;
      sel[rr] = (r < KSEL_) && (cond_mask[b * N_ + n] != 0);
    }
    unsigned long long bal0 = __ballot(sel[0]);
    unsigned long long bal1 = __ballot(sel[1]);
    if ((tid & 63) == 0) { wcnt[g] = __popcll(bal0); wcnt[4 + g] = __popcll(bal1); }
    __syncthreads();
    int off0 = 0, off4 = 0, total = 0;
    #pragma unroll
    for (int c = 0; c < 8; ++c) {
      int cc = wcnt[c];
      total += cc;
      if (c < g) off0 += cc;
      if (c < 4 + g) off4 += cc;
    }
    unsigned long long lmask = (1ull << (tid & 63)) - 1ull;
    if (sel[0]) idxb[b * N_ + off0 + __popcll(bal0 & lmask)] = tid;
    if (sel[1]) idxb[b * N_ + off4 + __popcll(bal1 & lmask)] = tid + 256;
    if (total == 0) {
      if (rank[0] == 0) idxb[b * N_] = tid;
      if (rank[1] == 0) idxb[b * N_] = tid + 256;
    }
    if (tid == 0) cnt[b] = (total == 0) ? 1 : total;
  }
  grid_barrier(bar, 2 * NBLK_);

  // ---------- P3: q-proj + compacted K-proj + compacted V^T-proj ----------
  {
    short* As = (short*)smem_raw;
    short* Bs = As + 12288;
    if (bid < 96) {
      int b = bid / 12, j = bid % 12;
      int mt = j >> 2, ntile = j & 3;
      int cv = cnt[b], padded = (cv + 63) & ~63;
      if (mt * 128 < padded)
        gemm_body<0, 1, 0, 4>(cond_b + (size_t)b * N_ * KV_, Wk_b, bk, Kc + (size_t)b * N_ * KV_,
                              As, Bs, (size_t)mt * 128, (size_t)ntile * 128, KV_, KV_,
                              idxb + b * N_, cv);
    } else if (bid < 192) {
      int i = bid - 96, b = i / 12, j = i % 12;
      int mtd = j & 3, ntc = j >> 2;
      int cv = cnt[b], padded = (cv + 63) & ~63;
      if (ntc * 128 < padded)
        gemm_body<3, 0, 1, 4>(Wv_b, cond_b + (size_t)b * N_ * KV_, bv, Vtc + (size_t)b * 512 * N_,
                              As, Bs, (size_t)mtd * 128, (size_t)ntc * 128, KV_, N_,
                              idxb + b * N_, cv);
    } else if (bid < 448) {
      int i = bid - 192;
      gemm_body<0, 0, 0, 4>(hT, Wq_b, bq, qb, As, Bs,
                            (size_t)(i & 63) * 128, (size_t)(i >> 6) * 128, C_, KV_, nullptr, 0);
    }
  }
  grid_barrier(bar, 3 * NBLK_);

  // ---------- P4: flash attention, 64 q-rows/job, 2 jobs/block ----------
  {
    short* Qs  = (short*)smem_raw;   // 4096 shorts; reused as Ps after Q frags in regs
    short* KsB = Qs + 4096;          // 2 x 4096
    short* VsB = KsB + 8192;         // 2 x 4096
    short* Ps  = Qs;
    int lane = tid & 63, wid = tid >> 6;
    int hi = lane >> 4, q = lane & 15;
    int swz = (lane & 7) << 3;
    for (int it = 0; it < 2; ++it) {
      int job = bid * 2 + it;              // (bh 0..63) x (qt 0..15); consecutive jobs share bh
      int bh = job >> 4, qt = job & 15;
      int b = bh >> 3, h = bh & 7;
      int s0 = qt * 64;
      int cntv = cnt[b];
      int nt = (cntv + 63) >> 6;
      const short* Qg = qb + ((size_t)(b * S_ + s0) * KV_ + h * DH_);
      const short* Kg = Kc + ((size_t)(b * N_) * KV_ + h * DH_);
      const short* Vg = Vtc + ((size_t)b * 512 + h * DH_) * N_;

      stage_tile64(Qg, KV_, Qs, wid, lane);
      stage_tile64(Kg, KV_, KsB, wid, lane);
      stage_tile64(Vg, N_, VsB, wid, lane);
      asm volatile("s_waitcnt vmcnt(0)" ::: "memory");
      __syncthreads();

      bf16x8 qf0 = *(const bf16x8*)&Qs[(wid * 16 + q) * 64 + ((hi * 8) ^ swz)];
      bf16x8 qf1 = *(const bf16x8*)&Qs[(wid * 16 + q) * 64 + ((32 + hi * 8) ^ swz)];

      float m = -1e30f, l = 0.f;
      f32x4 o[4] = {};

      for (int t = 0; t < nt; ++t) {
        int cur = t & 1;
        const short* Kcur = KsB + cur * 4096;
        const short* Vcur = VsB + cur * 4096;
        if (t + 1 < nt) {
          stage_tile64(Kg + (size_t)(t + 1) * 64 * KV_, KV_, KsB + (cur ^ 1) * 4096, wid, lane);
          stage_tile64(Vg + (t + 1) * 64, N_, VsB + (cur ^ 1) * 4096, wid, lane);
        }
        f32x4 pv[4];
        __builtin_amdgcn_s_setprio(1);
        #pragma unroll
        for (int kf = 0; kf < 4; ++kf) {
          bf16x8 k0 = *(const bf16x8*)&Kcur[(kf * 16 + q) * 64 + ((hi * 8) ^ swz)];
          bf16x8 k1 = *(const bf16x8*)&Kcur[(kf * 16 + q) * 64 + ((32 + hi * 8) ^ swz)];
          f32x4 z = {0.f, 0.f, 0.f, 0.f};
          pv[kf] = __builtin_amdgcn_mfma_f32_16x16x32_bf16(k0, qf0, z, 0, 0, 0);
          pv[kf] = __builtin_amdgcn_mfma_f32_16x16x32_bf16(k1, qf1, pv[kf], 0, 0, 0);
        }
        __builtin_amdgcn_s_setprio(0);
        float sv[16];
        int kbase = t * 64 + hi * 4;
        #pragma unroll
        for (int kf = 0; kf < 4; ++kf) {
          #pragma unroll
          for (int r = 0; r < 4; ++r)
            sv[kf * 4 + r] = (kbase + kf * 16 + r < cntv) ? pv[kf][r] * QK2L : -1e30f;
        }
        float tmax = sv[0];
        #pragma unroll
        for (int i = 1; i < 16; ++i) tmax = fmaxf(tmax, sv[i]);
        tmax = fmaxf(tmax, __shfl_xor(tmax, 16));
        tmax = fmaxf(tmax, __shfl_xor(tmax, 32));
        float mnew = fmaxf(m, tmax);
        float scale = exp2f(m - mnew);
        float psum = 0.f;
        #pragma unroll
        for (int i = 0; i < 16; ++i) { sv[i] = exp2f(sv[i] - mnew); psum += sv[i]; }
        psum += __shfl_xor(psum, 16);
        psum += __shfl_xor(psum, 32);
        l = l * scale + psum;
        m = mnew;
        #pragma unroll
        for (int df = 0; df < 4; ++df) {
          o[df][0] *= scale; o[df][1] *= scale; o[df][2] *= scale; o[df][3] *= scale;
        }
        int pbase = wid * 1024 + q * 64;
        #pragma unroll
        for (int kf = 0; kf < 4; ++kf) {
          short4v pk = { f2bf(sv[kf * 4 + 0]), f2bf(sv[kf * 4 + 1]), f2bf(sv[kf * 4 + 2]), f2bf(sv[kf * 4 + 3]) };
          *(short4v*)&Ps[pbase + ((kf * 16 + hi * 4) ^ swz)] = pk;
        }
        __builtin_amdgcn_s_setprio(1);
        #pragma unroll
        for (int ks = 0; ks < 2; ++ks) {
          bf16x8 pb = *(const bf16x8*)&Ps[pbase + ((ks * 32 + hi * 8) ^ swz)];
          #pragma unroll
          for (int df = 0; df < 4; ++df) {
            bf16x8 vf = *(const bf16x8*)&Vcur[(df * 16 + q) * 64 + ((ks * 32 + hi * 8) ^ swz)];
            o[df] = __builtin_amdgcn_mfma_f32_16x16x32_bf16(vf, pb, o[df], 0, 0, 0);
          }
        }
        __builtin_amdgcn_s_setprio(0);
        asm volatile("s_waitcnt vmcnt(0)" ::: "memory");
        __syncthreads();
      }
      float inv = 1.0f / l;
      short* op = attn_b + ((size_t)(b * S_ + s0 + wid * 16 + q) * KV_ + h * DH_);
      #pragma unroll
      for (int df = 0; df < 4; ++df) {
        short4v ov = { f2bf(o[df][0] * inv), f2bf(o[df][1] * inv), f2bf(o[df][2] * inv), f2bf(o[df][3] * inv) };
        *(short4v*)&op[df * 16 + hi * 4] = ov;
      }
    }
  }
  grid_barrier(bar, 4 * NBLK_);

  // ---------- P5: output projection -> (B,C,S), 256 jobs (WM=2) ----------
  if (bid < 256) {
    short* As = (short*)smem_raw;
    short* Bs = As + 6144;
    gemm_body<1, 0, 0, 2>(Wo_b, attn_b, bo, out, As, Bs,
                          (size_t)(bid & 3) * 64, (size_t)(bid >> 2) * 128, KV_, B_ * S_, nullptr, 0);
  }
}

extern "C" void kernel_launch(void* const* d_in, const int* in_sizes, int n_in,
                              void* d_out, int out_size, void* d_ws, size_t ws_size,
                              hipStream_t stream) {
  const float* h         = (const float*)d_in[0];
  const float* cond      = (const float*)d_in[1];
  const int*   cond_mask = (const int*)d_in[2];
  const float* Wq = (const float*)d_in[3];
  const float* bq = (const float*)d_in[4];
  const float* Wk = (const float*)d_in[5];
  const float* bk = (const float*)d_in[6];
  const float* Wv = (const float*)d_in[7];
  const float* bv = (const float*)d_in[8];
  const float* Wrk = (const float*)d_in[11];
  const float* brk = (const float*)d_in[12];
  const float* Wo  = (const float*)d_in[13];
  const float* bo  = (const float*)d_in[14];
  float* out = (float*)d_out;

  char* w = (char*)d_ws;
  short* qb      = (short*)(w + 0);          // 8 MB
  short* Kc      = (short*)(w + 8388608);    // 4 MB
  short* Vtc     = (short*)(w + 12582912);   // 4 MB
  short* attn_b  = (short*)(w + 16777216);   // 8 MB
  short* hT      = (short*)(w + 25165824);   // 4 MB
  short* cond_b  = (short*)(w + 29360128);   // 4 MB
  float* cp_part = (float*)(w + 33554432);   // 8 MB
  float* cp      = (float*)(w + 41943040);   // 1 MB
  int*   idxb    = (int*)  (w + 42991616);   // 16 KB
  int*   cnt     = (int*)  (w + 43008000);   // 64 B
  short* Wq_b    = (short*)(w + 43008064);   // 256 KB
  short* Wk_b    = (short*)(w + 43270208);   // 512 KB
  short* Wv_b    = (short*)(w + 43794496);   // 512 KB
  short* Wo_b    = (short*)(w + 44318784);   // 256 KB
  int*   bar     = (int*)  (w + 44580928);   // 16 B barrier counter

  hipMemsetAsync(bar, 0, 16, stream);
  // L1: converts + h-transpose + selector rel-proj
  k_prep<<<5376, 256, 0, stream>>>(cond, Wq, Wk, Wv, Wo, h, Wrk,
                                   cond_b, Wq_b, Wk_b, Wv_b, Wo_b, hT, cp_part);
  // L2: persistent mega kernel (normalize -> select -> proj -> attn -> outproj)
  k_mega<<<NBLK_, 256, 0, stream>>>(cp_part, brk, cp, cond_mask, idxb, cnt, hT, cond_b,
                                    Wq_b, Wk_b, Wv_b, bq, bk, bv, qb, Kc, Vtc,
                                    attn_b, Wo_b, bo, out, bar);
}

// Round 14
// 96.972 us; speedup vs baseline: 3.8552x; 3.8552x over previous
//
#include <hip/hip_runtime.h>
#include <math.h>

#define B_ 8
#define C_ 256
#define S_ 1024
#define N_ 512
#define KV_ 512
#define REL_ 64
#define NH_ 8
#define DH_ 64
#define KSEL_ 307

typedef __attribute__((ext_vector_type(8))) short bf16x8;
typedef __attribute__((ext_vector_type(4))) short short4v;
typedef __attribute__((ext_vector_type(4))) float f32x4;

__device__ __forceinline__ short f2bf(float f) {
  unsigned int u = __float_as_uint(f);
  u += 0x7fffu + ((u >> 16) & 1u);
  return (short)(u >> 16);
}

// ==================== L1: converts + h-transpose + rel-proj (split-K x8) ====================
__global__ __launch_bounds__(256) void k_prep(const float* __restrict__ cond, const float* __restrict__ Wq,
                                              const float* __restrict__ Wk, const float* __restrict__ Wv,
                                              const float* __restrict__ Wo, const float* __restrict__ h,
                                              const float* __restrict__ Wrk,
                                              short* __restrict__ cond_b, short* __restrict__ Wq_b,
                                              short* __restrict__ Wk_b, short* __restrict__ Wv_b,
                                              short* __restrict__ Wo_b, short* __restrict__ hT,
                                              float* __restrict__ cp_part) {
  __shared__ float fs[2176];
  int blk = blockIdx.x, tid = threadIdx.x;
  if (blk < 2816) {
    const float* src; short* dst; int base;
    if (blk < 2048)      { src = cond; dst = cond_b; base = blk; }
    else if (blk < 2176) { src = Wq;   dst = Wq_b;   base = blk - 2048; }
    else if (blk < 2432) { src = Wk;   dst = Wk_b;   base = blk - 2176; }
    else if (blk < 2688) { src = Wv;   dst = Wv_b;   base = blk - 2432; }
    else                 { src = Wo;   dst = Wo_b;   base = blk - 2688; }
    int i = base * 256 + tid;
    float4 v = ((const float4*)src)[i];
    short4v o = { f2bf(v.x), f2bf(v.y), f2bf(v.z), f2bf(v.w) };
    ((short4v*)dst)[i] = o;
  } else if (blk < 4864) {
    int i = blk - 2816;
    int s0 = (i & 31) * 32, c0 = ((i >> 5) & 7) * 32, b = i >> 8;
    int x = tid & 31, y0 = tid >> 5;
    #pragma unroll
    for (int y = y0; y < 32; y += 8)
      fs[y * 33 + x] = h[((size_t)(b * C_ + c0 + y)) * S_ + s0 + x];
    __syncthreads();
    #pragma unroll
    for (int y = y0; y < 32; y += 8)
      hT[((size_t)(b * S_ + s0 + y)) * C_ + c0 + x] = f2bf(fs[x * 33 + y]);
  } else {
    int i = blk - 4864;             // 0..511
    int bm = (i & 63) * 64, kb = i >> 6;
    float* As = fs;
    float* Bs = fs + 1088;
    int tm = (tid >> 4) << 2, tn = (tid & 15) << 2;
    float acc[4][4] = {};
    for (int k0 = kb * 64; k0 < kb * 64 + 64; k0 += 16) {
      #pragma unroll
      for (int ii = 0; ii < 4; ++ii) {
        int idx = tid + ii * 256;
        int r = idx >> 4, k = idx & 15;
        As[r * 17 + k] = cond[(size_t)(bm + r) * KV_ + k0 + k];
        Bs[r * 17 + k] = Wrk[(size_t)r * KV_ + k0 + k];
      }
      __syncthreads();
      #pragma unroll
      for (int k = 0; k < 16; ++k) {
        float a[4], bb[4];
        #pragma unroll
        for (int x = 0; x < 4; ++x) { a[x] = As[(tm + x) * 17 + k]; bb[x] = Bs[(tn + x) * 17 + k]; }
        #pragma unroll
        for (int x = 0; x < 4; ++x)
          #pragma unroll
          for (int y = 0; y < 4; ++y)
            acc[x][y] += a[x] * bb[y];
      }
      __syncthreads();
    }
    #pragma unroll
    for (int x = 0; x < 4; ++x)
      #pragma unroll
      for (int y = 0; y < 4; ++y)
        cp_part[(size_t)kb * 262144 + (size_t)(bm + tm + x) * 64 + tn + y] = acc[x][y];
  }
}

// ==================== L2a: reduce 8 split-K partials + bias + L2-normalize ====================
__global__ __launch_bounds__(256) void k_normalize(const float* __restrict__ cp_part, const float* __restrict__ brk,
                                                   float* __restrict__ cp) {
  int row = blockIdx.x * 4 + (threadIdx.x >> 6);
  int d = threadIdx.x & 63;
  size_t off = (size_t)row * 64 + d;
  float x = brk[d];
  #pragma unroll
  for (int s = 0; s < 8; ++s) x += cp_part[(size_t)s * 262144 + off];
  float ss = x * x;
  #pragma unroll
  for (int o = 32; o; o >>= 1) ss += __shfl_xor(ss, o);
  cp[off] = x / fmaxf(sqrtf(ss), 1e-12f);
}

// ==================== L2b: centrality + top-k + mask + fallback + index compaction ====================
__global__ __launch_bounds__(512) void k_select(const float* __restrict__ cp, const int* __restrict__ mask,
                                                int* __restrict__ idxb, int* __restrict__ cnt) {
  int b = blockIdx.x, tid = threadIdx.x;
  __shared__ float part[8][64];
  __shared__ float vsum[64];
  __shared__ float sc[512];
  __shared__ int wcnt[8];
  int d = tid & 63, g = tid >> 6;
  float sacc = 0.f;
  for (int n = g * 64; n < g * 64 + 64; ++n)
    sacc += cp[((size_t)b * N_ + n) * 64 + d];
  part[g][d] = sacc;
  __syncthreads();
  if (tid < 64) {
    float v = 0.f;
    #pragma unroll
    for (int gg = 0; gg < 8; ++gg) v += part[gg][tid];
    vsum[tid] = v;
  }
  __syncthreads();
  const float* x = cp + ((size_t)b * N_ + tid) * 64;
  float dsum = 0.f, dself = 0.f;
  #pragma unroll
  for (int dd = 0; dd < 64; ++dd) {
    float xv = x[dd];
    dsum += xv * vsum[dd];
    dself += xv * xv;
  }
  sc[tid] = dsum - dself;
  __syncthreads();
  float v = sc[tid];
  int rank = 0;
  for (int j = 0; j < N_; ++j) {
    float u = sc[j];
    rank += (u > v) || (u == v && j < tid);
  }
  int sel = (rank < KSEL_) && (mask[b * N_ + tid] != 0);
  unsigned long long bal = __ballot(sel);
  if ((tid & 63) == 0) wcnt[g] = __popcll(bal);
  __syncthreads();
  int off2 = 0, total = 0;
  #pragma unroll
  for (int i = 0; i < 8; ++i) { int c = wcnt[i]; total += c; if (i < g) off2 += c; }
  int pos = off2 + __popcll(bal & ((1ull << (tid & 63)) - 1ull));
  if (sel) idxb[b * N_ + pos] = tid;
  if (total == 0 && rank == 0) idxb[b * N_] = tid;
  if (tid == 0) cnt[b] = (total == 0) ? 1 : total;
}

// ==================== MFMA GEMM body: (WM*32)x128 tile, BK=32, 3-buf counted-vmcnt pipeline ====================
template<int MODE, int GA, int GB, int WM>
__device__ __forceinline__ void gemm_body(const short* __restrict__ A, const short* __restrict__ W,
                                          const float* __restrict__ bias, void* __restrict__ Cout,
                                          short* As, short* Bs, size_t bm, size_t bn, int Kd, int Nout,
                                          const int* __restrict__ gidx, int cntv) {
  constexpr int BMv = WM * 32;
  constexpr int NIA = BMv / 64;
  constexpr int OPS = NIA + 2;
  int tid = threadIdx.x;
  int lane = tid & 63, wid = tid >> 6;
  int wr = wid >> 1, wc = wid & 1;
  f32x4 acc[WM][4] = {};
  int srow = lane >> 2;
  int schunk = lane & 3;
  int steps = Kd >> 5;

  int rowA[NIA ? NIA : 1], rowB[2];
  #pragma unroll
  for (int i = 0; i < NIA; ++i) {
    int rt = wid * (WM * 8) + i * 16 + srow;
    rowA[i] = GA ? (((int)bm + rt < cntv) ? gidx[bm + rt] : 0) : (int)(bm + rt);
  }
  #pragma unroll
  for (int i = 0; i < 2; ++i) {
    int rt = wid * 32 + i * 16 + srow;
    rowB[i] = GB ? (((int)bn + rt < cntv) ? gidx[bn + rt] : 0) : (int)(bn + rt);
  }

  #define STAGE_G(t, buf)                                                                              \
    {                                                                                                  \
      int k0s = (t) * 32;                                                                              \
      _Pragma("unroll")                                                                                \
      for (int i = 0; i < NIA; ++i) {                                                                  \
        int rt = wid * (WM * 8) + i * 16 + srow;                                                       \
        int sc_ = (schunk ^ ((rt >> 1) & 3)) * 8;                                                      \
        const short* ga = A + (size_t)rowA[i] * Kd + k0s + sc_;                                        \
        __builtin_amdgcn_global_load_lds((const __attribute__((address_space(1))) void*)ga,            \
            (__attribute__((address_space(3))) void*)(As + (buf) * (BMv * 32) +                        \
                                                     (wid * (WM * 8) + i * 16) * 32),                  \
            16, 0, 0);                                                                                 \
      }                                                                                                \
      _Pragma("unroll")                                                                                \
      for (int i = 0; i < 2; ++i) {                                                                    \
        int rt = wid * 32 + i * 16 + srow;                                                             \
        int sc_ = (schunk ^ ((rt >> 1) & 3)) * 8;                                                      \
        const short* gb = W + (size_t)rowB[i] * Kd + k0s + sc_;                                        \
        __builtin_amdgcn_global_load_lds((const __attribute__((address_space(1))) void*)gb,            \
            (__attribute__((address_space(3))) void*)(Bs + (buf) * 4096 + (wid * 32 + i * 16) * 32),   \
            16, 0, 0);                                                                                 \
      }                                                                                                \
    }

  STAGE_G(0, 0);
  STAGE_G(1, 1);

  int cur = 0;
  for (int t = 0; t < steps; ++t) {
    if (t == steps - 1)
      asm volatile("s_waitcnt vmcnt(0)" ::: "memory");
    else
      asm volatile("s_waitcnt vmcnt(%0)" :: "n"(OPS) : "memory");
    __syncthreads();
    if (t + 2 < steps) {
      int nb = cur + 2; if (nb >= 3) nb -= 3;
      STAGE_G(t + 2, nb);
    }
    const short* Ac = As + cur * (BMv * 32);
    const short* Bc = Bs + cur * 4096;
    bf16x8 a[WM], b[4];
    #pragma unroll
    for (int m = 0; m < WM; ++m) {
      int rt = wr * (WM * 16) + m * 16 + (lane & 15);
      a[m] = *(const bf16x8*)(Ac + rt * 32 + (((lane >> 4) ^ ((rt >> 1) & 3)) * 8));
    }
    #pragma unroll
    for (int n = 0; n < 4; ++n) {
      int rt = wc * 64 + n * 16 + (lane & 15);
      b[n] = *(const bf16x8*)(Bc + rt * 32 + (((lane >> 4) ^ ((rt >> 1) & 3)) * 8));
    }
    __builtin_amdgcn_s_setprio(1);
    #pragma unroll
    for (int m = 0; m < WM; ++m)
      #pragma unroll
      for (int n = 0; n < 4; ++n)
        acc[m][n] = __builtin_amdgcn_mfma_f32_16x16x32_bf16(a[m], b[n], acc[m][n], 0, 0, 0);
    __builtin_amdgcn_s_setprio(0);
    cur = (cur == 2) ? 0 : cur + 1;
  }
  #undef STAGE_G

  int c0 = lane & 15, r0q = lane >> 4;
  #pragma unroll
  for (int n = 0; n < 4; ++n) {
    size_t col = bn + wc * 64 + n * 16 + c0;
    #pragma unroll
    for (int m = 0; m < WM; ++m) {
      #pragma unroll
      for (int j = 0; j < 4; ++j) {
        size_t row = bm + wr * (WM * 16) + m * 16 + r0q * 4 + j;
        if (MODE == 0) {
          ((short*)Cout)[row * Nout + col] = f2bf(acc[m][n][j] + bias[col]);
        } else if (MODE == 1) {
          ((float*)Cout)[((col >> 10) * C_ + row) * S_ + (col & (S_ - 1))] = acc[m][n][j] + bias[row];
        } else {
          ((short*)Cout)[row * Nout + col] = f2bf(acc[m][n][j] + bias[row]);
        }
      }
    }
  }
}

// ==================== L3: compacted K-proj + compacted V^T-proj first, then q-proj ====================
__global__ __launch_bounds__(256) void k_fused_proj(const short* __restrict__ hT, const short* __restrict__ cond_b,
                                                    const short* __restrict__ Wq_b, const short* __restrict__ Wk_b,
                                                    const short* __restrict__ Wv_b,
                                                    const float* __restrict__ bq, const float* __restrict__ bk,
                                                    const float* __restrict__ bv,
                                                    short* __restrict__ qb, short* __restrict__ Kc,
                                                    short* __restrict__ Vtc,
                                                    const int* __restrict__ idxb, const int* __restrict__ cnt) {
  __shared__ short smem[24576];
  int blk = blockIdx.x;
  if (blk < 96) {
    int b = blk / 12, j = blk % 12;
    int mt = j >> 2, ntile = j & 3;
    int cv = cnt[b], padded = (cv + 63) & ~63;
    if (mt * 128 >= padded) return;
    gemm_body<0, 1, 0, 4>(cond_b + (size_t)b * N_ * KV_, Wk_b, bk, Kc + (size_t)b * N_ * KV_,
                          smem, smem + 12288, (size_t)mt * 128, (size_t)ntile * 128, KV_, KV_,
                          idxb + b * N_, cv);
  } else if (blk < 192) {
    int i = blk - 96, b = i / 12, j = i % 12;
    int mtd = j & 3, ntc = j >> 2;
    int cv = cnt[b], padded = (cv + 63) & ~63;
    if (ntc * 128 >= padded) return;
    gemm_body<3, 0, 1, 4>(Wv_b, cond_b + (size_t)b * N_ * KV_, bv, Vtc + (size_t)b * 512 * N_,
                          smem, smem + 12288, (size_t)mtd * 128, (size_t)ntc * 128, KV_, N_,
                          idxb + b * N_, cv);
  } else {
    int i = blk - 192;  // 0..255
    gemm_body<0, 0, 0, 4>(hT, Wq_b, bq, qb, smem, smem + 12288,
                          (size_t)(i & 63) * 128, (size_t)(i >> 6) * 128, C_, KV_, nullptr, 0);
  }
}

// ==================== staging helpers (layout: LDS[r][c] = G[r][c ^ (r&7)], 128-B rows) ====================
__device__ __forceinline__ void stage_tile64_w8(const short* gRowBase, int gStride, short* ldsBase, int wid, int lane) {
  int sub = lane >> 3;
  int colE = ((lane & 7) ^ sub) * 8;
  int r = wid * 8 + sub;
  const short* gp = gRowBase + (size_t)r * gStride + colE;
  __builtin_amdgcn_global_load_lds((const __attribute__((address_space(1))) void*)gp,
                                   (__attribute__((address_space(3))) void*)(ldsBase + wid * 512),
                                   16, 0, 0);
}

// ==================== L4: MFMA flash attention, 128 q/block, 8 waves, Q direct-to-reg ====================
#define QK2L 0.18033688f  // 0.125 * log2(e)
__global__ __launch_bounds__(512) void k_attn_mfma(const short* __restrict__ qb, const short* __restrict__ Kc,
                                                   const short* __restrict__ Vtc, const int* __restrict__ cnt,
                                                   short* __restrict__ attn_b) {
  __shared__ short Ps[8192];      // per-wave 1024-short P regions
  __shared__ short Ks[2][4096];
  __shared__ short Vs[2][4096];
  int g = blockIdx.x;
  int xcd = g & 7, li = g >> 3;
  int bh = xcd * 8 + (li >> 3);
  int qt = li & 7;
  int b = bh >> 3, h = bh & 7;
  int tid = threadIdx.x, lane = tid & 63, wid = tid >> 6;
  int hi = lane >> 4, q = lane & 15;
  int swz = (lane & 7) << 3;
  int s0 = qt * 128;
  int cntv = cnt[b];
  int nt = (cntv + 63) >> 6;
  const short* Qg = qb + ((size_t)(b * S_ + s0) * KV_ + h * DH_);
  const short* Kg = Kc + ((size_t)(b * N_) * KV_ + h * DH_);
  const short* Vg = Vtc + ((size_t)((b * NH_ + h) * DH_) * N_);

  // Q fragments straight from global (contiguous 16B per lane; XOR swizzle cancels on this path)
  bf16x8 qf0 = *(const bf16x8*)(Qg + (size_t)(wid * 16 + q) * KV_ + hi * 8);
  bf16x8 qf1 = *(const bf16x8*)(Qg + (size_t)(wid * 16 + q) * KV_ + 32 + hi * 8);

  stage_tile64_w8(Kg, KV_, Ks[0], wid, lane);
  stage_tile64_w8(Vg, N_, Vs[0], wid, lane);
  asm volatile("s_waitcnt vmcnt(0)" ::: "memory");
  __syncthreads();

  float m = -1e30f, l = 0.f;
  f32x4 o[4] = {};

  for (int t = 0; t < nt; ++t) {
    int cur = t & 1;
    const short* Kcur = Ks[cur];
    const short* Vcur = Vs[cur];
    if (t + 1 < nt) {
      stage_tile64_w8(Kg + (size_t)(t + 1) * 64 * KV_, KV_, Ks[cur ^ 1], wid, lane);
      stage_tile64_w8(Vg + (t + 1) * 64, N_, Vs[cur ^ 1], wid, lane);
    }
    f32x4 pv[4];
    __builtin_amdgcn_s_setprio(1);
    #pragma unroll
    for (int kf = 0; kf < 4; ++kf) {
      bf16x8 k0 = *(const bf16x8*)&Kcur[(kf * 16 + q) * 64 + ((hi * 8) ^ swz)];
      bf16x8 k1 = *(const bf16x8*)&Kcur[(kf * 16 + q) * 64 + ((32 + hi * 8) ^ swz)];
      f32x4 z = {0.f, 0.f, 0.f, 0.f};
      pv[kf] = __builtin_amdgcn_mfma_f32_16x16x32_bf16(k0, qf0, z, 0, 0, 0);
      pv[kf] = __builtin_amdgcn_mfma_f32_16x16x32_bf16(k1, qf1, pv[kf], 0, 0, 0);
    }
    __builtin_amdgcn_s_setprio(0);
    float sv[16];
    int kbase = t * 64 + hi * 4;
    #pragma unroll
    for (int kf = 0; kf < 4; ++kf) {
      #pragma unroll
      for (int r = 0; r < 4; ++r)
        sv[kf * 4 + r] = (kbase + kf * 16 + r < cntv) ? pv[kf][r] * QK2L : -1e30f;
    }
    float tmax = sv[0];
    #pragma unroll
    for (int i = 1; i < 16; ++i) tmax = fmaxf(tmax, sv[i]);
    tmax = fmaxf(tmax, __shfl_xor(tmax, 16));
    tmax = fmaxf(tmax, __shfl_xor(tmax, 32));
    float mnew = fmaxf(m, tmax);
    float scale = exp2f(m - mnew);
    float psum = 0.f;
    #pragma unroll
    for (int i = 0; i < 16; ++i) { sv[i] = exp2f(sv[i] - mnew); psum += sv[i]; }
    psum += __shfl_xor(psum, 16);
    psum += __shfl_xor(psum, 32);
    l = l * scale + psum;
    m = mnew;
    #pragma unroll
    for (int df = 0; df < 4; ++df) {
      o[df][0] *= scale; o[df][1] *= scale; o[df][2] *= scale; o[df][3] *= scale;
    }
    int pbase = wid * 1024 + q * 64;
    #pragma unroll
    for (int kf = 0; kf < 4; ++kf) {
      short4v pk = { f2bf(sv[kf * 4 + 0]), f2bf(sv[kf * 4 + 1]), f2bf(sv[kf * 4 + 2]), f2bf(sv[kf * 4 + 3]) };
      *(short4v*)&Ps[pbase + ((kf * 16 + hi * 4) ^ swz)] = pk;
    }
    __builtin_amdgcn_s_setprio(1);
    #pragma unroll
    for (int ks = 0; ks < 2; ++ks) {
      bf16x8 pb = *(const bf16x8*)&Ps[pbase + ((ks * 32 + hi * 8) ^ swz)];
      #pragma unroll
      for (int df = 0; df < 4; ++df) {
        bf16x8 vf = *(const bf16x8*)&Vcur[(df * 16 + q) * 64 + ((ks * 32 + hi * 8) ^ swz)];
        o[df] = __builtin_amdgcn_mfma_f32_16x16x32_bf16(vf, pb, o[df], 0, 0, 0);
      }
    }
    __builtin_amdgcn_s_setprio(0);
    if (t + 1 < nt) {  // last iter: no prefetch pending, epilogue is register-only
      asm volatile("s_waitcnt vmcnt(0)" ::: "memory");
      __syncthreads();
    }
  }
  float inv = 1.0f / l;
  short* op = attn_b + ((size_t)(b * S_ + s0 + wid * 16 + q) * KV_ + h * DH_);
  #pragma unroll
  for (int df = 0; df < 4; ++df) {
    short4v ov = { f2bf(o[df][0] * inv), f2bf(o[df][1] * inv), f2bf(o[df][2] * inv), f2bf(o[df][3] * inv) };
    *(short4v*)&op[df * 16 + hi * 4] = ov;
  }
}

// ==================== L5: output projection, BM=64, XCD-grouped 1-D grid (256 blocks) ====================
__global__ __launch_bounds__(256) void k_outproj(const short* __restrict__ Wo_b, const short* __restrict__ attn_b,
                                                 const float* __restrict__ bo, float* __restrict__ out) {
  __shared__ short smem[18432];  // A 3x2048 + B 3x4096
  // bid -> (bm tile i 0..3, bn panel p 0..63); the 4 i-blocks of each p land on one XCD
  int bid = blockIdx.x;
  int xcd = bid & 7, j = bid >> 3;
  int p = ((j >> 2) << 3) | xcd;
  int i = j & 3;
  gemm_body<1, 0, 0, 2>(Wo_b, attn_b, bo, out, smem, smem + 6144,
                        (size_t)i * 64, (size_t)p * 128, KV_, B_ * S_, nullptr, 0);
}

extern "C" void kernel_launch(void* const* d_in, const int* in_sizes, int n_in,
                              void* d_out, int out_size, void* d_ws, size_t ws_size,
                              hipStream_t stream) {
  const float* h         = (const float*)d_in[0];
  const float* cond      = (const float*)d_in[1];
  const int*   cond_mask = (const int*)d_in[2];
  const float* Wq = (const float*)d_in[3];
  const float* bq = (const float*)d_in[4];
  const float* Wk = (const float*)d_in[5];
  const float* bk = (const float*)d_in[6];
  const float* Wv = (const float*)d_in[7];
  const float* bv = (const float*)d_in[8];
  const float* Wrk = (const float*)d_in[11];
  const float* brk = (const float*)d_in[12];
  const float* Wo  = (const float*)d_in[13];
  const float* bo  = (const float*)d_in[14];
  float* out = (float*)d_out;

  char* w = (char*)d_ws;
  short* qb      = (short*)(w + 0);          // 8 MB
  short* Kc      = (short*)(w + 8388608);    // 4 MB
  short* Vtc     = (short*)(w + 12582912);   // 4 MB
  short* attn_b  = (short*)(w + 16777216);   // 8 MB
  short* hT      = (short*)(w + 25165824);   // 4 MB
  short* cond_b  = (short*)(w + 29360128);   // 4 MB
  float* cp_part = (float*)(w + 33554432);   // 8 MB
  float* cp      = (float*)(w + 41943040);   // 1 MB
  int*   idxb    = (int*)  (w + 42991616);   // 16 KB
  int*   cnt     = (int*)  (w + 43008000);   // 64 B
  short* Wq_b    = (short*)(w + 43008064);   // 256 KB
  short* Wk_b    = (short*)(w + 43270208);   // 512 KB
  short* Wv_b    = (short*)(w + 43794496);   // 512 KB
  short* Wo_b    = (short*)(w + 44318784);   // 256 KB

  // L1: converts + h-transpose + selector rel-proj (split-K x8)
  k_prep<<<5376, 256, 0, stream>>>(cond, Wq, Wk, Wv, Wo, h, Wrk,
                                   cond_b, Wq_b, Wk_b, Wv_b, Wo_b, hT, cp_part);
  // L2a: normalize (parallel, 1 wave/row)
  k_normalize<<<1024, 256, 0, stream>>>(cp_part, brk, cp);
  // L2b: centrality + top-k + compaction
  k_select<<<8, 512, 0, stream>>>(cp, cond_mask, idxb, cnt);
  // L3: compacted K/V^T-proj (stragglers first) + q-proj  (3-buf counted-vmcnt pipeline)
  k_fused_proj<<<448, 256, 0, stream>>>(hT, cond_b, Wq_b, Wk_b, Wv_b, bq, bk, bv,
                                        qb, Kc, Vtc, idxb, cnt);
  // L4: attention over compacted keys (128 q/block, XCD-grouped, Q direct-to-reg)
  k_attn_mfma<<<512, 512, 0, stream>>>(qb, Kc, Vtc, cnt, attn_b);
  // L5: output projection -> (B,C,S), 256 blocks XCD-grouped
  k_outproj<<<256, 256, 0, stream>>>(Wo_b, attn_b, bo, out);
}

// Round 15
// 95.849 us; speedup vs baseline: 3.9004x; 1.0117x over previous
//
#include <hip/hip_runtime.h>
#include <math.h>

#define B_ 8
#define C_ 256
#define S_ 1024
#define N_ 512
#define KV_ 512
#define REL_ 64
#define NH_ 8
#define DH_ 64
#define KSEL_ 307

typedef __attribute__((ext_vector_type(8))) short bf16x8;
typedef __attribute__((ext_vector_type(4))) short short4v;
typedef __attribute__((ext_vector_type(4))) float f32x4;

__device__ __forceinline__ short f2bf(float f) {
  unsigned int u = __float_as_uint(f);
  u += 0x7fffu + ((u >> 16) & 1u);
  return (short)(u >> 16);
}

// ==================== L1: converts (32B/thread) + h-transpose + rel-proj (split-K x8) ====================
__global__ __launch_bounds__(256) void k_prep(const float* __restrict__ cond, const float* __restrict__ Wq,
                                              const float* __restrict__ Wk, const float* __restrict__ Wv,
                                              const float* __restrict__ Wo, const float* __restrict__ h,
                                              const float* __restrict__ Wrk,
                                              short* __restrict__ cond_b, short* __restrict__ Wq_b,
                                              short* __restrict__ Wk_b, short* __restrict__ Wv_b,
                                              short* __restrict__ Wo_b, short* __restrict__ hT,
                                              float* __restrict__ cp_part) {
  __shared__ float fs[2176];
  int blk = blockIdx.x, tid = threadIdx.x;
  if (blk < 1408) {
    // ---- f32 -> bf16 converts, 8 elems (32B read / 16B write) per thread ----
    const float* src; short* dst; int base;
    if (blk < 1024)      { src = cond; dst = cond_b; base = blk; }
    else if (blk < 1088) { src = Wq;   dst = Wq_b;   base = blk - 1024; }
    else if (blk < 1216) { src = Wk;   dst = Wk_b;   base = blk - 1088; }
    else if (blk < 1344) { src = Wv;   dst = Wv_b;   base = blk - 1216; }
    else                 { src = Wo;   dst = Wo_b;   base = blk - 1344; }
    int j = base * 256 + tid;
    float4 v0 = ((const float4*)src)[j * 2];
    float4 v1 = ((const float4*)src)[j * 2 + 1];
    bf16x8 o = { f2bf(v0.x), f2bf(v0.y), f2bf(v0.z), f2bf(v0.w),
                 f2bf(v1.x), f2bf(v1.y), f2bf(v1.z), f2bf(v1.w) };
    ((bf16x8*)dst)[j] = o;
  } else if (blk < 3456) {
    int i = blk - 1408;
    int s0 = (i & 31) * 32, c0 = ((i >> 5) & 7) * 32, b = i >> 8;
    int x = tid & 31, y0 = tid >> 5;
    #pragma unroll
    for (int y = y0; y < 32; y += 8)
      fs[y * 33 + x] = h[((size_t)(b * C_ + c0 + y)) * S_ + s0 + x];
    __syncthreads();
    #pragma unroll
    for (int y = y0; y < 32; y += 8)
      hT[((size_t)(b * S_ + s0 + y)) * C_ + c0 + x] = f2bf(fs[x * 33 + y]);
  } else {
    int i = blk - 3456;             // 0..511
    int bm = (i & 63) * 64, kb = i >> 6;   // kb 0..7, K slice of 64
    float* As = fs;
    float* Bs = fs + 1088;
    int tm = (tid >> 4) << 2, tn = (tid & 15) << 2;
    float acc[4][4] = {};
    for (int k0 = kb * 64; k0 < kb * 64 + 64; k0 += 16) {
      #pragma unroll
      for (int ii = 0; ii < 4; ++ii) {
        int idx = tid + ii * 256;
        int r = idx >> 4, k = idx & 15;
        As[r * 17 + k] = cond[(size_t)(bm + r) * KV_ + k0 + k];
        Bs[r * 17 + k] = Wrk[(size_t)r * KV_ + k0 + k];
      }
      __syncthreads();
      #pragma unroll
      for (int k = 0; k < 16; ++k) {
        float a[4], bb[4];
        #pragma unroll
        for (int x = 0; x < 4; ++x) { a[x] = As[(tm + x) * 17 + k]; bb[x] = Bs[(tn + x) * 17 + k]; }
        #pragma unroll
        for (int x = 0; x < 4; ++x)
          #pragma unroll
          for (int y = 0; y < 4; ++y)
            acc[x][y] += a[x] * bb[y];
      }
      __syncthreads();
    }
    #pragma unroll
    for (int x = 0; x < 4; ++x)
      #pragma unroll
      for (int y = 0; y < 4; ++y)
        cp_part[(size_t)kb * 262144 + (size_t)(bm + tm + x) * 64 + tn + y] = acc[x][y];
  }
}

// ==================== L2a: reduce 8 split-K partials + bias + L2-normalize ====================
__global__ __launch_bounds__(256) void k_normalize(const float* __restrict__ cp_part, const float* __restrict__ brk,
                                                   float* __restrict__ cp) {
  int row = blockIdx.x * 4 + (threadIdx.x >> 6);
  int d = threadIdx.x & 63;
  size_t off = (size_t)row * 64 + d;
  float x = brk[d];
  #pragma unroll
  for (int s = 0; s < 8; ++s) x += cp_part[(size_t)s * 262144 + off];
  float ss = x * x;
  #pragma unroll
  for (int o = 32; o; o >>= 1) ss += __shfl_xor(ss, o);
  cp[off] = x / fmaxf(sqrtf(ss), 1e-12f);
}

// ==================== L2b: centrality + top-k + mask + fallback + index compaction ====================
__global__ __launch_bounds__(512) void k_select(const float* __restrict__ cp, const int* __restrict__ mask,
                                                int* __restrict__ idxb, int* __restrict__ cnt) {
  int b = blockIdx.x, tid = threadIdx.x;
  __shared__ float part[8][64];
  __shared__ float vsum[64];
  __shared__ float sc[512];
  __shared__ int wcnt[8];
  int d = tid & 63, g = tid >> 6;
  float sacc = 0.f;
  for (int n = g * 64; n < g * 64 + 64; ++n)
    sacc += cp[((size_t)b * N_ + n) * 64 + d];
  part[g][d] = sacc;
  __syncthreads();
  if (tid < 64) {
    float v = 0.f;
    #pragma unroll
    for (int gg = 0; gg < 8; ++gg) v += part[gg][tid];
    vsum[tid] = v;
  }
  __syncthreads();
  const float* x = cp + ((size_t)b * N_ + tid) * 64;
  float dsum = 0.f, dself = 0.f;
  #pragma unroll
  for (int dd = 0; dd < 64; ++dd) {
    float xv = x[dd];
    dsum += xv * vsum[dd];
    dself += xv * xv;
  }
  sc[tid] = dsum - dself;
  __syncthreads();
  float v = sc[tid];
  int rank = 0;
  for (int j = 0; j < N_; ++j) {
    float u = sc[j];
    rank += (u > v) || (u == v && j < tid);
  }
  int sel = (rank < KSEL_) && (mask[b * N_ + tid] != 0);
  unsigned long long bal = __ballot(sel);
  if ((tid & 63) == 0) wcnt[g] = __popcll(bal);
  __syncthreads();
  int off2 = 0, total = 0;
  #pragma unroll
  for (int i = 0; i < 8; ++i) { int c = wcnt[i]; total += c; if (i < g) off2 += c; }
  int pos = off2 + __popcll(bal & ((1ull << (tid & 63)) - 1ull));
  if (sel) idxb[b * N_ + pos] = tid;
  if (total == 0 && rank == 0) idxb[b * N_] = tid;
  if (tid == 0) cnt[b] = (total == 0) ? 1 : total;
}

// ==================== MFMA GEMM body: (WM*32)x128 tile, BK=32, 3-buf counted-vmcnt pipeline ====================
template<int MODE, int GA, int GB, int WM>
__device__ __forceinline__ void gemm_body(const short* __restrict__ A, const short* __restrict__ W,
                                          const float* __restrict__ bias, void* __restrict__ Cout,
                                          short* As, short* Bs, size_t bm, size_t bn, int Kd, int Nout,
                                          const int* __restrict__ gidx, int cntv) {
  constexpr int BMv = WM * 32;
  constexpr int NIA = BMv / 64;
  constexpr int OPS = NIA + 2;
  int tid = threadIdx.x;
  int lane = tid & 63, wid = tid >> 6;
  int wr = wid >> 1, wc = wid & 1;
  f32x4 acc[WM][4] = {};
  int srow = lane >> 2;
  int schunk = lane & 3;
  int steps = Kd >> 5;

  int rowA[NIA ? NIA : 1], rowB[2];
  #pragma unroll
  for (int i = 0; i < NIA; ++i) {
    int rt = wid * (WM * 8) + i * 16 + srow;
    rowA[i] = GA ? (((int)bm + rt < cntv) ? gidx[bm + rt] : 0) : (int)(bm + rt);
  }
  #pragma unroll
  for (int i = 0; i < 2; ++i) {
    int rt = wid * 32 + i * 16 + srow;
    rowB[i] = GB ? (((int)bn + rt < cntv) ? gidx[bn + rt] : 0) : (int)(bn + rt);
  }

  #define STAGE_G(t, buf)                                                                              \
    {                                                                                                  \
      int k0s = (t) * 32;                                                                              \
      _Pragma("unroll")                                                                                \
      for (int i = 0; i < NIA; ++i) {                                                                  \
        int rt = wid * (WM * 8) + i * 16 + srow;                                                       \
        int sc_ = (schunk ^ ((rt >> 1) & 3)) * 8;                                                      \
        const short* ga = A + (size_t)rowA[i] * Kd + k0s + sc_;                                        \
        __builtin_amdgcn_global_load_lds((const __attribute__((address_space(1))) void*)ga,            \
            (__attribute__((address_space(3))) void*)(As + (buf) * (BMv * 32) +                        \
                                                     (wid * (WM * 8) + i * 16) * 32),                  \
            16, 0, 0);                                                                                 \
      }                                                                                                \
      _Pragma("unroll")                                                                                \
      for (int i = 0; i < 2; ++i) {                                                                    \
        int rt = wid * 32 + i * 16 + srow;                                                             \
        int sc_ = (schunk ^ ((rt >> 1) & 3)) * 8;                                                      \
        const short* gb = W + (size_t)rowB[i] * Kd + k0s + sc_;                                        \
        __builtin_amdgcn_global_load_lds((const __attribute__((address_space(1))) void*)gb,            \
            (__attribute__((address_space(3))) void*)(Bs + (buf) * 4096 + (wid * 32 + i * 16) * 32),   \
            16, 0, 0);                                                                                 \
      }                                                                                                \
    }

  STAGE_G(0, 0);
  STAGE_G(1, 1);

  int cur = 0;
  for (int t = 0; t < steps; ++t) {
    if (t == steps - 1)
      asm volatile("s_waitcnt vmcnt(0)" ::: "memory");
    else
      asm volatile("s_waitcnt vmcnt(%0)" :: "n"(OPS) : "memory");
    __syncthreads();
    if (t + 2 < steps) {
      int nb = cur + 2; if (nb >= 3) nb -= 3;
      STAGE_G(t + 2, nb);
    }
    const short* Ac = As + cur * (BMv * 32);
    const short* Bc = Bs + cur * 4096;
    bf16x8 a[WM], b[4];
    #pragma unroll
    for (int m = 0; m < WM; ++m) {
      int rt = wr * (WM * 16) + m * 16 + (lane & 15);
      a[m] = *(const bf16x8*)(Ac + rt * 32 + (((lane >> 4) ^ ((rt >> 1) & 3)) * 8));
    }
    #pragma unroll
    for (int n = 0; n < 4; ++n) {
      int rt = wc * 64 + n * 16 + (lane & 15);
      b[n] = *(const bf16x8*)(Bc + rt * 32 + (((lane >> 4) ^ ((rt >> 1) & 3)) * 8));
    }
    __builtin_amdgcn_s_setprio(1);
    #pragma unroll
    for (int m = 0; m < WM; ++m)
      #pragma unroll
      for (int n = 0; n < 4; ++n)
        acc[m][n] = __builtin_amdgcn_mfma_f32_16x16x32_bf16(a[m], b[n], acc[m][n], 0, 0, 0);
    __builtin_amdgcn_s_setprio(0);
    cur = (cur == 2) ? 0 : cur + 1;
  }
  #undef STAGE_G

  int c0 = lane & 15, r0q = lane >> 4;
  #pragma unroll
  for (int n = 0; n < 4; ++n) {
    size_t col = bn + wc * 64 + n * 16 + c0;
    #pragma unroll
    for (int m = 0; m < WM; ++m) {
      #pragma unroll
      for (int j = 0; j < 4; ++j) {
        size_t row = bm + wr * (WM * 16) + m * 16 + r0q * 4 + j;
        if (MODE == 0) {
          ((short*)Cout)[row * Nout + col] = f2bf(acc[m][n][j] + bias[col]);
        } else if (MODE == 1) {
          ((float*)Cout)[((col >> 10) * C_ + row) * S_ + (col & (S_ - 1))] = acc[m][n][j] + bias[row];
        } else {
          ((short*)Cout)[row * Nout + col] = f2bf(acc[m][n][j] + bias[row]);
        }
      }
    }
  }
}

// ==================== L3: compacted K-proj + V^T-proj (WM=2, balanced) + q-proj (WM=4) ====================
__global__ __launch_bounds__(256) void k_fused_proj(const short* __restrict__ hT, const short* __restrict__ cond_b,
                                                    const short* __restrict__ Wq_b, const short* __restrict__ Wk_b,
                                                    const short* __restrict__ Wv_b,
                                                    const float* __restrict__ bq, const float* __restrict__ bk,
                                                    const float* __restrict__ bv,
                                                    short* __restrict__ qb, short* __restrict__ Kc,
                                                    short* __restrict__ Vtc,
                                                    const int* __restrict__ idxb, const int* __restrict__ cnt) {
  __shared__ short smem[24576];
  int blk = blockIdx.x;
  if (blk < 192) {
    // K-proj: WM=2 (64-row tiles), 24 jobs/batch
    int b = blk / 24, j = blk % 24;
    int mt = j >> 2, ntile = j & 3;       // mt 0..5, ntile 0..3
    int cv = cnt[b], padded = (cv + 63) & ~63;
    if (mt * 64 >= padded) return;
    gemm_body<0, 1, 0, 2>(cond_b + (size_t)b * N_ * KV_, Wk_b, bk, Kc + (size_t)b * N_ * KV_,
                          smem, smem + 12288, (size_t)mt * 64, (size_t)ntile * 128, KV_, KV_,
                          idxb + b * N_, cv);
  } else if (blk < 384) {
    // V^T-proj: WM=2, 24 jobs/batch (mtd 0..7 x ntc 0..2)
    int i = blk - 192, b = i / 24, j = i % 24;
    int ntc = j >> 3, mtd = j & 7;
    int cv = cnt[b], padded = (cv + 63) & ~63;
    if (ntc * 128 >= padded) return;
    gemm_body<3, 0, 1, 2>(Wv_b, cond_b + (size_t)b * N_ * KV_, bv, Vtc + (size_t)b * 512 * N_,
                          smem, smem + 12288, (size_t)mtd * 64, (size_t)ntc * 128, KV_, N_,
                          idxb + b * N_, cv);
  } else {
    int i = blk - 384;  // 0..255
    gemm_body<0, 0, 0, 4>(hT, Wq_b, bq, qb, smem, smem + 12288,
                          (size_t)(i & 63) * 128, (size_t)(i >> 6) * 128, C_, KV_, nullptr, 0);
  }
}

// ==================== staging helpers (layout: LDS[r][c] = G[r][c ^ (r&7)], 128-B rows) ====================
__device__ __forceinline__ void stage_tile64_w8(const short* gRowBase, int gStride, short* ldsBase, int wid, int lane) {
  int sub = lane >> 3;
  int colE = ((lane & 7) ^ sub) * 8;
  int r = wid * 8 + sub;
  const short* gp = gRowBase + (size_t)r * gStride + colE;
  __builtin_amdgcn_global_load_lds((const __attribute__((address_space(1))) void*)gp,
                                   (__attribute__((address_space(3))) void*)(ldsBase + wid * 512),
                                   16, 0, 0);
}

// ==================== L4: MFMA flash attention, 128 q/block, 8 waves, Q direct-to-reg ====================
#define QK2L 0.18033688f  // 0.125 * log2(e)
__global__ __launch_bounds__(512) void k_attn_mfma(const short* __restrict__ qb, const short* __restrict__ Kc,
                                                   const short* __restrict__ Vtc, const int* __restrict__ cnt,
                                                   short* __restrict__ attn_b) {
  __shared__ short Ps[8192];
  __shared__ short Ks[2][4096];
  __shared__ short Vs[2][4096];
  int g = blockIdx.x;
  int xcd = g & 7, li = g >> 3;
  int bh = xcd * 8 + (li >> 3);
  int qt = li & 7;
  int b = bh >> 3, h = bh & 7;
  int tid = threadIdx.x, lane = tid & 63, wid = tid >> 6;
  int hi = lane >> 4, q = lane & 15;
  int swz = (lane & 7) << 3;
  int s0 = qt * 128;
  int cntv = cnt[b];
  int nt = (cntv + 63) >> 6;
  const short* Qg = qb + ((size_t)(b * S_ + s0) * KV_ + h * DH_);
  const short* Kg = Kc + ((size_t)(b * N_) * KV_ + h * DH_);
  const short* Vg = Vtc + ((size_t)((b * NH_ + h) * DH_) * N_);

  bf16x8 qf0 = *(const bf16x8*)(Qg + (size_t)(wid * 16 + q) * KV_ + hi * 8);
  bf16x8 qf1 = *(const bf16x8*)(Qg + (size_t)(wid * 16 + q) * KV_ + 32 + hi * 8);

  stage_tile64_w8(Kg, KV_, Ks[0], wid, lane);
  stage_tile64_w8(Vg, N_, Vs[0], wid, lane);
  asm volatile("s_waitcnt vmcnt(0)" ::: "memory");
  __syncthreads();

  float m = -1e30f, l = 0.f;
  f32x4 o[4] = {};

  for (int t = 0; t < nt; ++t) {
    int cur = t & 1;
    const short* Kcur = Ks[cur];
    const short* Vcur = Vs[cur];
    if (t + 1 < nt) {
      stage_tile64_w8(Kg + (size_t)(t + 1) * 64 * KV_, KV_, Ks[cur ^ 1], wid, lane);
      stage_tile64_w8(Vg + (t + 1) * 64, N_, Vs[cur ^ 1], wid, lane);
    }
    f32x4 pv[4];
    __builtin_amdgcn_s_setprio(1);
    #pragma unroll
    for (int kf = 0; kf < 4; ++kf) {
      bf16x8 k0 = *(const bf16x8*)&Kcur[(kf * 16 + q) * 64 + ((hi * 8) ^ swz)];
      bf16x8 k1 = *(const bf16x8*)&Kcur[(kf * 16 + q) * 64 + ((32 + hi * 8) ^ swz)];
      f32x4 z = {0.f, 0.f, 0.f, 0.f};
      pv[kf] = __builtin_amdgcn_mfma_f32_16x16x32_bf16(k0, qf0, z, 0, 0, 0);
      pv[kf] = __builtin_amdgcn_mfma_f32_16x16x32_bf16(k1, qf1, pv[kf], 0, 0, 0);
    }
    __builtin_amdgcn_s_setprio(0);
    float sv[16];
    int kbase = t * 64 + hi * 4;
    #pragma unroll
    for (int kf = 0; kf < 4; ++kf) {
      #pragma unroll
      for (int r = 0; r < 4; ++r)
        sv[kf * 4 + r] = (kbase + kf * 16 + r < cntv) ? pv[kf][r] * QK2L : -1e30f;
    }
    float tmax = sv[0];
    #pragma unroll
    for (int i = 1; i < 16; ++i) tmax = fmaxf(tmax, sv[i]);
    tmax = fmaxf(tmax, __shfl_xor(tmax, 16));
    tmax = fmaxf(tmax, __shfl_xor(tmax, 32));
    float mnew = fmaxf(m, tmax);
    float scale = exp2f(m - mnew);
    float psum = 0.f;
    #pragma unroll
    for (int i = 0; i < 16; ++i) { sv[i] = exp2f(sv[i] - mnew); psum += sv[i]; }
    psum += __shfl_xor(psum, 16);
    psum += __shfl_xor(psum, 32);
    l = l * scale + psum;
    m = mnew;
    #pragma unroll
    for (int df = 0; df < 4; ++df) {
      o[df][0] *= scale; o[df][1] *= scale; o[df][2] *= scale; o[df][3] *= scale;
    }
    int pbase = wid * 1024 + q * 64;
    #pragma unroll
    for (int kf = 0; kf < 4; ++kf) {
      short4v pk = { f2bf(sv[kf * 4 + 0]), f2bf(sv[kf * 4 + 1]), f2bf(sv[kf * 4 + 2]), f2bf(sv[kf * 4 + 3]) };
      *(short4v*)&Ps[pbase + ((kf * 16 + hi * 4) ^ swz)] = pk;
    }
    __builtin_amdgcn_s_setprio(1);
    #pragma unroll
    for (int ks = 0; ks < 2; ++ks) {
      bf16x8 pb = *(const bf16x8*)&Ps[pbase + ((ks * 32 + hi * 8) ^ swz)];
      #pragma unroll
      for (int df = 0; df < 4; ++df) {
        bf16x8 vf = *(const bf16x8*)&Vcur[(df * 16 + q) * 64 + ((ks * 32 + hi * 8) ^ swz)];
        o[df] = __builtin_amdgcn_mfma_f32_16x16x32_bf16(vf, pb, o[df], 0, 0, 0);
      }
    }
    __builtin_amdgcn_s_setprio(0);
    if (t + 1 < nt) {
      asm volatile("s_waitcnt vmcnt(0)" ::: "memory");
      __syncthreads();
    }
  }
  float inv = 1.0f / l;
  short* op = attn_b + ((size_t)(b * S_ + s0 + wid * 16 + q) * KV_ + h * DH_);
  #pragma unroll
  for (int df = 0; df < 4; ++df) {
    short4v ov = { f2bf(o[df][0] * inv), f2bf(o[df][1] * inv), f2bf(o[df][2] * inv), f2bf(o[df][3] * inv) };
    *(short4v*)&op[df * 16 + hi * 4] = ov;
  }
}

// ==================== L5: output projection, BM=64, XCD-grouped 1-D grid (256 blocks) ====================
__global__ __launch_bounds__(256) void k_outproj(const short* __restrict__ Wo_b, const short* __restrict__ attn_b,
                                                 const float* __restrict__ bo, float* __restrict__ out) {
  __shared__ short smem[18432];
  int bid = blockIdx.x;
  int xcd = bid & 7, j = bid >> 3;
  int p = ((j >> 2) << 3) | xcd;
  int i = j & 3;
  gemm_body<1, 0, 0, 2>(Wo_b, attn_b, bo, out, smem, smem + 6144,
                        (size_t)i * 64, (size_t)p * 128, KV_, B_ * S_, nullptr, 0);
}

extern "C" void kernel_launch(void* const* d_in, const int* in_sizes, int n_in,
                              void* d_out, int out_size, void* d_ws, size_t ws_size,
                              hipStream_t stream) {
  const float* h         = (const float*)d_in[0];
  const float* cond      = (const float*)d_in[1];
  const int*   cond_mask = (const int*)d_in[2];
  const float* Wq = (const float*)d_in[3];
  const float* bq = (const float*)d_in[4];
  const float* Wk = (const float*)d_in[5];
  const float* bk = (const float*)d_in[6];
  const float* Wv = (const float*)d_in[7];
  const float* bv = (const float*)d_in[8];
  const float* Wrk = (const float*)d_in[11];
  const float* brk = (const float*)d_in[12];
  const float* Wo  = (const float*)d_in[13];
  const float* bo  = (const float*)d_in[14];
  float* out = (float*)d_out;

  char* w = (char*)d_ws;
  short* qb      = (short*)(w + 0);          // 8 MB
  short* Kc      = (short*)(w + 8388608);    // 4 MB
  short* Vtc     = (short*)(w + 12582912);   // 4 MB
  short* attn_b  = (short*)(w + 16777216);   // 8 MB
  short* hT      = (short*)(w + 25165824);   // 4 MB
  short* cond_b  = (short*)(w + 29360128);   // 4 MB
  float* cp_part = (float*)(w + 33554432);   // 8 MB
  float* cp      = (float*)(w + 41943040);   // 1 MB
  int*   idxb    = (int*)  (w + 42991616);   // 16 KB
  int*   cnt     = (int*)  (w + 43008000);   // 64 B
  short* Wq_b    = (short*)(w + 43008064);   // 256 KB
  short* Wk_b    = (short*)(w + 43270208);   // 512 KB
  short* Wv_b    = (short*)(w + 43794496);   // 512 KB
  short* Wo_b    = (short*)(w + 44318784);   // 256 KB

  // L1: converts + h-transpose + selector rel-proj (split-K x8)
  k_prep<<<3968, 256, 0, stream>>>(cond, Wq, Wk, Wv, Wo, h, Wrk,
                                   cond_b, Wq_b, Wk_b, Wv_b, Wo_b, hT, cp_part);
  // L2a: normalize (parallel, 1 wave/row)
  k_normalize<<<1024, 256, 0, stream>>>(cp_part, brk, cp);
  // L2b: centrality + top-k + compaction
  k_select<<<8, 512, 0, stream>>>(cp, cond_mask, idxb, cnt);
  // L3: balanced K/V^T-proj (WM=2) + q-proj (WM=4), 640 blocks all-resident
  k_fused_proj<<<640, 256, 0, stream>>>(hT, cond_b, Wq_b, Wk_b, Wv_b, bq, bk, bv,
                                        qb, Kc, Vtc, idxb, cnt);
  // L4: attention over compacted keys (128 q/block, XCD-grouped, Q direct-to-reg)
  k_attn_mfma<<<512, 512, 0, stream>>>(qb, Kc, Vtc, cnt, attn_b);
  // L5: output projection -> (B,C,S), 256 blocks XCD-grouped
  k_outproj<<<256, 256, 0, stream>>>(Wo_b, attn_b, bo, out);
}

// Round 16
// 91.634 us; speedup vs baseline: 4.0798x; 1.0460x over previous
//
#include <hip/hip_runtime.h>
#include <math.h>

#define B_ 8
#define C_ 256
#define S_ 1024
#define N_ 512
#define KV_ 512
#define REL_ 64
#define NH_ 8
#define DH_ 64
#define KSEL_ 307

typedef __attribute__((ext_vector_type(8))) short bf16x8;
typedef __attribute__((ext_vector_type(4))) short short4v;
typedef __attribute__((ext_vector_type(4))) float f32x4;

__device__ __forceinline__ short f2bf(float f) {
  unsigned int u = __float_as_uint(f);
  u += 0x7fffu + ((u >> 16) & 1u);
  return (short)(u >> 16);
}

// ==================== L1: rel-proj (straggler-first) + h-transpose 64x64 + converts ====================
__global__ __launch_bounds__(256) void k_prep(const float* __restrict__ cond, const float* __restrict__ Wq,
                                              const float* __restrict__ Wk, const float* __restrict__ Wv,
                                              const float* __restrict__ Wo, const float* __restrict__ h,
                                              const float* __restrict__ Wrk,
                                              short* __restrict__ cond_b, short* __restrict__ Wq_b,
                                              short* __restrict__ Wk_b, short* __restrict__ Wv_b,
                                              short* __restrict__ Wo_b, short* __restrict__ hT,
                                              float* __restrict__ cp_part) {
  __shared__ float fs[4160];  // 64x65 transpose tile / rel-proj 2x(64x17)
  int blk = blockIdx.x, tid = threadIdx.x;
  if (blk < 512) {
    // ---- rel-proj f32 split-K x8 (longest jobs first) ----
    int bm = (blk & 63) * 64, kb = blk >> 6;   // kb 0..7, K slice of 64
    float* As = fs;
    float* Bs = fs + 1088;
    int tm = (tid >> 4) << 2, tn = (tid & 15) << 2;
    float acc[4][4] = {};
    for (int k0 = kb * 64; k0 < kb * 64 + 64; k0 += 16) {
      #pragma unroll
      for (int ii = 0; ii < 4; ++ii) {
        int idx = tid + ii * 256;
        int r = idx >> 4, k = idx & 15;
        As[r * 17 + k] = cond[(size_t)(bm + r) * KV_ + k0 + k];
        Bs[r * 17 + k] = Wrk[(size_t)r * KV_ + k0 + k];
      }
      __syncthreads();
      #pragma unroll
      for (int k = 0; k < 16; ++k) {
        float a[4], bb[4];
        #pragma unroll
        for (int x = 0; x < 4; ++x) { a[x] = As[(tm + x) * 17 + k]; bb[x] = Bs[(tn + x) * 17 + k]; }
        #pragma unroll
        for (int x = 0; x < 4; ++x)
          #pragma unroll
          for (int y = 0; y < 4; ++y)
            acc[x][y] += a[x] * bb[y];
      }
      __syncthreads();
    }
    #pragma unroll
    for (int x = 0; x < 4; ++x)
      #pragma unroll
      for (int y = 0; y < 4; ++y)
        cp_part[(size_t)kb * 262144 + (size_t)(bm + tm + x) * 64 + tn + y] = acc[x][y];
  } else if (blk < 1024) {
    // ---- transpose h: (B,C,S) f32 -> (B,S,C) bf16, 64x64 tiles ----
    int i = blk - 512;                 // 0..511
    int s0 = (i & 15) * 64, c0 = ((i >> 4) & 3) * 64, b = i >> 6;
    int x = tid & 63, y0 = tid >> 6;   // 4 waves sweep 64 rows
    #pragma unroll
    for (int y = y0; y < 64; y += 4)
      fs[y * 65 + x] = h[((size_t)(b * C_ + c0 + y)) * S_ + s0 + x];
    __syncthreads();
    #pragma unroll
    for (int y = y0; y < 64; y += 4)
      hT[((size_t)(b * S_ + s0 + y)) * C_ + c0 + x] = f2bf(fs[x * 65 + y]);
  } else {
    // ---- f32 -> bf16 converts, 8 elems per thread ----
    int base = blk - 1024;             // 0..1407
    const float* src; short* dst;
    if (base < 1024)      { src = cond; dst = cond_b; }
    else if (base < 1088) { src = Wq;   dst = Wq_b;   base -= 1024; }
    else if (base < 1216) { src = Wk;   dst = Wk_b;   base -= 1088; }
    else if (base < 1344) { src = Wv;   dst = Wv_b;   base -= 1216; }
    else                  { src = Wo;   dst = Wo_b;   base -= 1344; }
    int j = base * 256 + tid;
    float4 v0 = ((const float4*)src)[j * 2];
    float4 v1 = ((const float4*)src)[j * 2 + 1];
    bf16x8 o = { f2bf(v0.x), f2bf(v0.y), f2bf(v0.z), f2bf(v0.w),
                 f2bf(v1.x), f2bf(v1.y), f2bf(v1.z), f2bf(v1.w) };
    ((bf16x8*)dst)[j] = o;
  }
}

// ==================== L2a: reduce 8 split-K partials + bias + L2-normalize ====================
__global__ __launch_bounds__(256) void k_normalize(const float* __restrict__ cp_part, const float* __restrict__ brk,
                                                   float* __restrict__ cp) {
  int row = blockIdx.x * 4 + (threadIdx.x >> 6);
  int d = threadIdx.x & 63;
  size_t off = (size_t)row * 64 + d;
  float x = brk[d];
  #pragma unroll
  for (int s = 0; s < 8; ++s) x += cp_part[(size_t)s * 262144 + off];
  float ss = x * x;
  #pragma unroll
  for (int o = 32; o; o >>= 1) ss += __shfl_xor(ss, o);
  cp[off] = x / fmaxf(sqrtf(ss), 1e-12f);
}

// ==================== L2b: centrality + top-k + mask + fallback + index compaction ====================
__global__ __launch_bounds__(512) void k_select(const float* __restrict__ cp, const int* __restrict__ mask,
                                                int* __restrict__ idxb, int* __restrict__ cnt) {
  int b = blockIdx.x, tid = threadIdx.x;
  __shared__ float part[8][64];
  __shared__ float vsum[64];
  __shared__ float sc[512];
  __shared__ int wcnt[8];
  int d = tid & 63, g = tid >> 6;
  float sacc = 0.f;
  for (int n = g * 64; n < g * 64 + 64; ++n)
    sacc += cp[((size_t)b * N_ + n) * 64 + d];
  part[g][d] = sacc;
  __syncthreads();
  if (tid < 64) {
    float v = 0.f;
    #pragma unroll
    for (int gg = 0; gg < 8; ++gg) v += part[gg][tid];
    vsum[tid] = v;
  }
  __syncthreads();
  const float* x = cp + ((size_t)b * N_ + tid) * 64;
  float dsum = 0.f, dself = 0.f;
  #pragma unroll
  for (int dd = 0; dd < 64; ++dd) {
    float xv = x[dd];
    dsum += xv * vsum[dd];
    dself += xv * xv;
  }
  sc[tid] = dsum - dself;
  __syncthreads();
  float v = sc[tid];
  int rank = 0;
  for (int j = 0; j < N_; ++j) {
    float u = sc[j];
    rank += (u > v) || (u == v && j < tid);
  }
  int sel = (rank < KSEL_) && (mask[b * N_ + tid] != 0);
  unsigned long long bal = __ballot(sel);
  if ((tid & 63) == 0) wcnt[g] = __popcll(bal);
  __syncthreads();
  int off2 = 0, total = 0;
  #pragma unroll
  for (int i = 0; i < 8; ++i) { int c = wcnt[i]; total += c; if (i < g) off2 += c; }
  int pos = off2 + __popcll(bal & ((1ull << (tid & 63)) - 1ull));
  if (sel) idxb[b * N_ + pos] = tid;
  if (total == 0 && rank == 0) idxb[b * N_] = tid;
  if (tid == 0) cnt[b] = (total == 0) ? 1 : total;
}

// ==================== MFMA GEMM body: (WM*32)x128 tile, BK=32, 3-buf counted-vmcnt pipeline ====================
template<int MODE, int GA, int GB, int WM>
__device__ __forceinline__ void gemm_body(const short* __restrict__ A, const short* __restrict__ W,
                                          const float* __restrict__ bias, void* __restrict__ Cout,
                                          short* As, short* Bs, size_t bm, size_t bn, int Kd, int Nout,
                                          const int* __restrict__ gidx, int cntv) {
  constexpr int BMv = WM * 32;
  constexpr int NIA = BMv / 64;
  constexpr int OPS = NIA + 2;
  int tid = threadIdx.x;
  int lane = tid & 63, wid = tid >> 6;
  int wr = wid >> 1, wc = wid & 1;
  f32x4 acc[WM][4] = {};
  int srow = lane >> 2;
  int schunk = lane & 3;
  int steps = Kd >> 5;

  int rowA[NIA ? NIA : 1], rowB[2];
  #pragma unroll
  for (int i = 0; i < NIA; ++i) {
    int rt = wid * (WM * 8) + i * 16 + srow;
    rowA[i] = GA ? (((int)bm + rt < cntv) ? gidx[bm + rt] : 0) : (int)(bm + rt);
  }
  #pragma unroll
  for (int i = 0; i < 2; ++i) {
    int rt = wid * 32 + i * 16 + srow;
    rowB[i] = GB ? (((int)bn + rt < cntv) ? gidx[bn + rt] : 0) : (int)(bn + rt);
  }

  #define STAGE_G(t, buf)                                                                              \
    {                                                                                                  \
      int k0s = (t) * 32;                                                                              \
      _Pragma("unroll")                                                                                \
      for (int i = 0; i < NIA; ++i) {                                                                  \
        int rt = wid * (WM * 8) + i * 16 + srow;                                                       \
        int sc_ = (schunk ^ ((rt >> 1) & 3)) * 8;                                                      \
        const short* ga = A + (size_t)rowA[i] * Kd + k0s + sc_;                                        \
        __builtin_amdgcn_global_load_lds((const __attribute__((address_space(1))) void*)ga,            \
            (__attribute__((address_space(3))) void*)(As + (buf) * (BMv * 32) +                        \
                                                     (wid * (WM * 8) + i * 16) * 32),                  \
            16, 0, 0);                                                                                 \
      }                                                                                                \
      _Pragma("unroll")                                                                                \
      for (int i = 0; i < 2; ++i) {                                                                    \
        int rt = wid * 32 + i * 16 + srow;                                                             \
        int sc_ = (schunk ^ ((rt >> 1) & 3)) * 8;                                                      \
        const short* gb = W + (size_t)rowB[i] * Kd + k0s + sc_;                                        \
        __builtin_amdgcn_global_load_lds((const __attribute__((address_space(1))) void*)gb,            \
            (__attribute__((address_space(3))) void*)(Bs + (buf) * 4096 + (wid * 32 + i * 16) * 32),   \
            16, 0, 0);                                                                                 \
      }                                                                                                \
    }

  STAGE_G(0, 0);
  STAGE_G(1, 1);

  int cur = 0;
  for (int t = 0; t < steps; ++t) {
    if (t == steps - 1)
      asm volatile("s_waitcnt vmcnt(0)" ::: "memory");
    else
      asm volatile("s_waitcnt vmcnt(%0)" :: "n"(OPS) : "memory");
    __syncthreads();
    if (t + 2 < steps) {
      int nb = cur + 2; if (nb >= 3) nb -= 3;
      STAGE_G(t + 2, nb);
    }
    const short* Ac = As + cur * (BMv * 32);
    const short* Bc = Bs + cur * 4096;
    bf16x8 a[WM], b[4];
    #pragma unroll
    for (int m = 0; m < WM; ++m) {
      int rt = wr * (WM * 16) + m * 16 + (lane & 15);
      a[m] = *(const bf16x8*)(Ac + rt * 32 + (((lane >> 4) ^ ((rt >> 1) & 3)) * 8));
    }
    #pragma unroll
    for (int n = 0; n < 4; ++n) {
      int rt = wc * 64 + n * 16 + (lane & 15);
      b[n] = *(const bf16x8*)(Bc + rt * 32 + (((lane >> 4) ^ ((rt >> 1) & 3)) * 8));
    }
    #pragma unroll
    for (int m = 0; m < WM; ++m)
      #pragma unroll
      for (int n = 0; n < 4; ++n)
        acc[m][n] = __builtin_amdgcn_mfma_f32_16x16x32_bf16(a[m], b[n], acc[m][n], 0, 0, 0);
    cur = (cur == 2) ? 0 : cur + 1;
  }
  #undef STAGE_G

  int c0 = lane & 15, r0q = lane >> 4;
  #pragma unroll
  for (int n = 0; n < 4; ++n) {
    size_t col = bn + wc * 64 + n * 16 + c0;
    #pragma unroll
    for (int m = 0; m < WM; ++m) {
      #pragma unroll
      for (int j = 0; j < 4; ++j) {
        size_t row = bm + wr * (WM * 16) + m * 16 + r0q * 4 + j;
        if (MODE == 0) {
          ((short*)Cout)[row * Nout + col] = f2bf(acc[m][n][j] + bias[col]);
        } else if (MODE == 1) {
          ((float*)Cout)[((col >> 10) * C_ + row) * S_ + (col & (S_ - 1))] = acc[m][n][j] + bias[row];
        } else {
          ((short*)Cout)[row * Nout + col] = f2bf(acc[m][n][j] + bias[row]);
        }
      }
    }
  }
}

// ==================== L3: compacted K-proj + V^T-proj (WM=2, balanced) + q-proj (WM=4) ====================
__global__ __launch_bounds__(256) void k_fused_proj(const short* __restrict__ hT, const short* __restrict__ cond_b,
                                                    const short* __restrict__ Wq_b, const short* __restrict__ Wk_b,
                                                    const short* __restrict__ Wv_b,
                                                    const float* __restrict__ bq, const float* __restrict__ bk,
                                                    const float* __restrict__ bv,
                                                    short* __restrict__ qb, short* __restrict__ Kc,
                                                    short* __restrict__ Vtc,
                                                    const int* __restrict__ idxb, const int* __restrict__ cnt) {
  __shared__ short smem[24576];
  int blk = blockIdx.x;
  if (blk < 192) {
    int b = blk / 24, j = blk % 24;
    int mt = j >> 2, ntile = j & 3;
    int cv = cnt[b], padded = (cv + 63) & ~63;
    if (mt * 64 >= padded) return;
    gemm_body<0, 1, 0, 2>(cond_b + (size_t)b * N_ * KV_, Wk_b, bk, Kc + (size_t)b * N_ * KV_,
                          smem, smem + 12288, (size_t)mt * 64, (size_t)ntile * 128, KV_, KV_,
                          idxb + b * N_, cv);
  } else if (blk < 384) {
    int i = blk - 192, b = i / 24, j = i % 24;
    int ntc = j >> 3, mtd = j & 7;
    int cv = cnt[b], padded = (cv + 63) & ~63;
    if (ntc * 128 >= padded) return;
    gemm_body<3, 0, 1, 2>(Wv_b, cond_b + (size_t)b * N_ * KV_, bv, Vtc + (size_t)b * 512 * N_,
                          smem, smem + 12288, (size_t)mtd * 64, (size_t)ntc * 128, KV_, N_,
                          idxb + b * N_, cv);
  } else {
    int i = blk - 384;
    gemm_body<0, 0, 0, 4>(hT, Wq_b, bq, qb, smem, smem + 12288,
                          (size_t)(i & 63) * 128, (size_t)(i >> 6) * 128, C_, KV_, nullptr, 0);
  }
}

// ==================== staging helper (layout: LDS[r][c] = G[r][c ^ (r&7)], 128-B rows) ====================
__device__ __forceinline__ void stage_tile64_w8(const short* gRowBase, int gStride, short* ldsBase, int wid, int lane) {
  int sub = lane >> 3;
  int colE = ((lane & 7) ^ sub) * 8;
  int r = wid * 8 + sub;
  const short* gp = gRowBase + (size_t)r * gStride + colE;
  __builtin_amdgcn_global_load_lds((const __attribute__((address_space(1))) void*)gp,
                                   (__attribute__((address_space(3))) void*)(ldsBase + wid * 512),
                                   16, 0, 0);
}

// ==================== L4: MFMA flash attention, 128 q/block, 8 waves, Q direct-to-reg ====================
#define QK2L 0.18033688f  // 0.125 * log2(e)
__global__ __launch_bounds__(512) void k_attn_mfma(const short* __restrict__ qb, const short* __restrict__ Kc,
                                                   const short* __restrict__ Vtc, const int* __restrict__ cnt,
                                                   short* __restrict__ attn_b) {
  __shared__ short Ps[8192];
  __shared__ short Ks[2][4096];
  __shared__ short Vs[2][4096];
  int g = blockIdx.x;
  int xcd = g & 7, li = g >> 3;
  int bh = xcd * 8 + (li >> 3);
  int qt = li & 7;
  int b = bh >> 3, h = bh & 7;
  int tid = threadIdx.x, lane = tid & 63, wid = tid >> 6;
  int hi = lane >> 4, q = lane & 15;
  int swz = (lane & 7) << 3;
  int s0 = qt * 128;
  int cntv = cnt[b];
  int nt = (cntv + 63) >> 6;
  const short* Qg = qb + ((size_t)(b * S_ + s0) * KV_ + h * DH_);
  const short* Kg = Kc + ((size_t)(b * N_) * KV_ + h * DH_);
  const short* Vg = Vtc + ((size_t)((b * NH_ + h) * DH_) * N_);

  bf16x8 qf0 = *(const bf16x8*)(Qg + (size_t)(wid * 16 + q) * KV_ + hi * 8);
  bf16x8 qf1 = *(const bf16x8*)(Qg + (size_t)(wid * 16 + q) * KV_ + 32 + hi * 8);

  stage_tile64_w8(Kg, KV_, Ks[0], wid, lane);
  stage_tile64_w8(Vg, N_, Vs[0], wid, lane);
  asm volatile("s_waitcnt vmcnt(0)" ::: "memory");
  __syncthreads();

  float m = -1e30f, l = 0.f;
  f32x4 o[4] = {};

  for (int t = 0; t < nt; ++t) {
    int cur = t & 1;
    const short* Kcur = Ks[cur];
    const short* Vcur = Vs[cur];
    if (t + 1 < nt) {
      stage_tile64_w8(Kg + (size_t)(t + 1) * 64 * KV_, KV_, Ks[cur ^ 1], wid, lane);
      stage_tile64_w8(Vg + (t + 1) * 64, N_, Vs[cur ^ 1], wid, lane);
    }
    f32x4 pv[4];
    __builtin_amdgcn_s_setprio(1);
    #pragma unroll
    for (int kf = 0; kf < 4; ++kf) {
      bf16x8 k0 = *(const bf16x8*)&Kcur[(kf * 16 + q) * 64 + ((hi * 8) ^ swz)];
      bf16x8 k1 = *(const bf16x8*)&Kcur[(kf * 16 + q) * 64 + ((32 + hi * 8) ^ swz)];
      f32x4 z = {0.f, 0.f, 0.f, 0.f};
      pv[kf] = __builtin_amdgcn_mfma_f32_16x16x32_bf16(k0, qf0, z, 0, 0, 0);
      pv[kf] = __builtin_amdgcn_mfma_f32_16x16x32_bf16(k1, qf1, pv[kf], 0, 0, 0);
    }
    __builtin_amdgcn_s_setprio(0);
    float sv[16];
    int kbase = t * 64 + hi * 4;
    #pragma unroll
    for (int kf = 0; kf < 4; ++kf) {
      #pragma unroll
      for (int r = 0; r < 4; ++r)
        sv[kf * 4 + r] = (kbase + kf * 16 + r < cntv) ? pv[kf][r] * QK2L : -1e30f;
    }
    float tmax = sv[0];
    #pragma unroll
    for (int i = 1; i < 16; ++i) tmax = fmaxf(tmax, sv[i]);
    tmax = fmaxf(tmax, __shfl_xor(tmax, 16));
    tmax = fmaxf(tmax, __shfl_xor(tmax, 32));
    float mnew = fmaxf(m, tmax);
    float scale = exp2f(m - mnew);
    float psum = 0.f;
    #pragma unroll
    for (int i = 0; i < 16; ++i) { sv[i] = exp2f(sv[i] - mnew); psum += sv[i]; }
    psum += __shfl_xor(psum, 16);
    psum += __shfl_xor(psum, 32);
    l = l * scale + psum;
    m = mnew;
    #pragma unroll
    for (int df = 0; df < 4; ++df) {
      o[df][0] *= scale; o[df][1] *= scale; o[df][2] *= scale; o[df][3] *= scale;
    }
    int pbase = wid * 1024 + q * 64;
    #pragma unroll
    for (int kf = 0; kf < 4; ++kf) {
      short4v pk = { f2bf(sv[kf * 4 + 0]), f2bf(sv[kf * 4 + 1]), f2bf(sv[kf * 4 + 2]), f2bf(sv[kf * 4 + 3]) };
      *(short4v*)&Ps[pbase + ((kf * 16 + hi * 4) ^ swz)] = pk;
    }
    __builtin_amdgcn_s_setprio(1);
    #pragma unroll
    for (int ks = 0; ks < 2; ++ks) {
      bf16x8 pb = *(const bf16x8*)&Ps[pbase + ((ks * 32 + hi * 8) ^ swz)];
      #pragma unroll
      for (int df = 0; df < 4; ++df) {
        bf16x8 vf = *(const bf16x8*)&Vcur[(df * 16 + q) * 64 + ((ks * 32 + hi * 8) ^ swz)];
        o[df] = __builtin_amdgcn_mfma_f32_16x16x32_bf16(vf, pb, o[df], 0, 0, 0);
      }
    }
    __builtin_amdgcn_s_setprio(0);
    if (t + 1 < nt) {
      asm volatile("s_waitcnt vmcnt(0)" ::: "memory");
      __syncthreads();
    }
  }
  float inv = 1.0f / l;
  short* op = attn_b + ((size_t)(b * S_ + s0 + wid * 16 + q) * KV_ + h * DH_);
  #pragma unroll
  for (int df = 0; df < 4; ++df) {
    short4v ov = { f2bf(o[df][0] * inv), f2bf(o[df][1] * inv), f2bf(o[df][2] * inv), f2bf(o[df][3] * inv) };
    *(short4v*)&op[df * 16 + hi * 4] = ov;
  }
}

// ==================== L5: output projection, BM=64, XCD-grouped 1-D grid (256 blocks) ====================
__global__ __launch_bounds__(256) void k_outproj(const short* __restrict__ Wo_b, const short* __restrict__ attn_b,
                                                 const float* __restrict__ bo, float* __restrict__ out) {
  __shared__ short smem[18432];
  int bid = blockIdx.x;
  int xcd = bid & 7, j = bid >> 3;
  int p = ((j >> 2) << 3) | xcd;
  int i = j & 3;
  gemm_body<1, 0, 0, 2>(Wo_b, attn_b, bo, out, smem, smem + 6144,
                        (size_t)i * 64, (size_t)p * 128, KV_, B_ * S_, nullptr, 0);
}

extern "C" void kernel_launch(void* const* d_in, const int* in_sizes, int n_in,
                              void* d_out, int out_size, void* d_ws, size_t ws_size,
                              hipStream_t stream) {
  const float* h         = (const float*)d_in[0];
  const float* cond      = (const float*)d_in[1];
  const int*   cond_mask = (const int*)d_in[2];
  const float* Wq = (const float*)d_in[3];
  const float* bq = (const float*)d_in[4];
  const float* Wk = (const float*)d_in[5];
  const float* bk = (const float*)d_in[6];
  const float* Wv = (const float*)d_in[7];
  const float* bv = (const float*)d_in[8];
  const float* Wrk = (const float*)d_in[11];
  const float* brk = (const float*)d_in[12];
  const float* Wo  = (const float*)d_in[13];
  const float* bo  = (const float*)d_in[14];
  float* out = (float*)d_out;

  char* w = (char*)d_ws;
  short* qb      = (short*)(w + 0);          // 8 MB
  short* Kc      = (short*)(w + 8388608);    // 4 MB
  short* Vtc     = (short*)(w + 12582912);   // 4 MB
  short* attn_b  = (short*)(w + 16777216);   // 8 MB
  short* hT      = (short*)(w + 25165824);   // 4 MB
  short* cond_b  = (short*)(w + 29360128);   // 4 MB
  float* cp_part = (float*)(w + 33554432);   // 8 MB
  float* cp      = (float*)(w + 41943040);   // 1 MB
  int*   idxb    = (int*)  (w + 42991616);   // 16 KB
  int*   cnt     = (int*)  (w + 43008000);   // 64 B
  short* Wq_b    = (short*)(w + 43008064);   // 256 KB
  short* Wk_b    = (short*)(w + 43270208);   // 512 KB
  short* Wv_b    = (short*)(w + 43794496);   // 512 KB
  short* Wo_b    = (short*)(w + 44318784);   // 256 KB

  // L1: rel-proj (straggler-first) + h-transpose 64x64 + converts
  k_prep<<<2432, 256, 0, stream>>>(cond, Wq, Wk, Wv, Wo, h, Wrk,
                                   cond_b, Wq_b, Wk_b, Wv_b, Wo_b, hT, cp_part);
  // L2a: normalize (parallel, 1 wave/row)
  k_normalize<<<1024, 256, 0, stream>>>(cp_part, brk, cp);
  // L2b: centrality + top-k + compaction
  k_select<<<8, 512, 0, stream>>>(cp, cond_mask, idxb, cnt);
  // L3: balanced K/V^T-proj (WM=2) + q-proj (WM=4), 640 blocks all-resident
  k_fused_proj<<<640, 256, 0, stream>>>(hT, cond_b, Wq_b, Wk_b, Wv_b, bq, bk, bv,
                                        qb, Kc, Vtc, idxb, cnt);
  // L4: attention over compacted keys (128 q/block, XCD-grouped, Q direct-to-reg)
  k_attn_mfma<<<512, 512, 0, stream>>>(qb, Kc, Vtc, cnt, attn_b);
  // L5: output projection -> (B,C,S), 256 blocks XCD-grouped
  k_outproj<<<256, 256, 0, stream>>>(Wo_b, attn_b, bo, out);
}

// Round 17
// 88.395 us; speedup vs baseline: 4.2293x; 1.0366x over previous
//
#include <hip/hip_runtime.h>
#include <math.h>

#define B_ 8
#define C_ 256
#define S_ 1024
#define N_ 512
#define KV_ 512
#define REL_ 64
#define NH_ 8
#define DH_ 64
#define KSEL_ 307

typedef __attribute__((ext_vector_type(8))) short bf16x8;
typedef __attribute__((ext_vector_type(4))) short short4v;
typedef __attribute__((ext_vector_type(4))) float f32x4;

__device__ __forceinline__ short f2bf(float f) {
  unsigned int u = __float_as_uint(f);
  u += 0x7fffu + ((u >> 16) & 1u);
  return (short)(u >> 16);
}

// ==================== L1: rel-proj (split-K x4, straggler-first) + h-transpose 64x64 + converts ====================
__global__ __launch_bounds__(256) void k_prep(const float* __restrict__ cond, const float* __restrict__ Wq,
                                              const float* __restrict__ Wk, const float* __restrict__ Wv,
                                              const float* __restrict__ Wo, const float* __restrict__ h,
                                              const float* __restrict__ Wrk,
                                              short* __restrict__ cond_b, short* __restrict__ Wq_b,
                                              short* __restrict__ Wk_b, short* __restrict__ Wv_b,
                                              short* __restrict__ Wo_b, short* __restrict__ hT,
                                              float* __restrict__ cp_part) {
  __shared__ float fs[4160];  // 64x65 transpose tile / rel-proj 2x(64x17)
  int blk = blockIdx.x, tid = threadIdx.x;
  if (blk < 256) {
    // ---- rel-proj f32 split-K x4 (longest jobs first) ----
    int bm = (blk & 63) * 64, kb = blk >> 6;   // kb 0..3, K slice of 128
    float* As = fs;
    float* Bs = fs + 1088;
    int tm = (tid >> 4) << 2, tn = (tid & 15) << 2;
    float acc[4][4] = {};
    for (int k0 = kb * 128; k0 < kb * 128 + 128; k0 += 16) {
      #pragma unroll
      for (int ii = 0; ii < 4; ++ii) {
        int idx = tid + ii * 256;
        int r = idx >> 4, k = idx & 15;
        As[r * 17 + k] = cond[(size_t)(bm + r) * KV_ + k0 + k];
        Bs[r * 17 + k] = Wrk[(size_t)r * KV_ + k0 + k];
      }
      __syncthreads();
      #pragma unroll
      for (int k = 0; k < 16; ++k) {
        float a[4], bb[4];
        #pragma unroll
        for (int x = 0; x < 4; ++x) { a[x] = As[(tm + x) * 17 + k]; bb[x] = Bs[(tn + x) * 17 + k]; }
        #pragma unroll
        for (int x = 0; x < 4; ++x)
          #pragma unroll
          for (int y = 0; y < 4; ++y)
            acc[x][y] += a[x] * bb[y];
      }
      __syncthreads();
    }
    #pragma unroll
    for (int x = 0; x < 4; ++x)
      #pragma unroll
      for (int y = 0; y < 4; ++y)
        cp_part[(size_t)kb * 262144 + (size_t)(bm + tm + x) * 64 + tn + y] = acc[x][y];
  } else if (blk < 768) {
    // ---- transpose h: (B,C,S) f32 -> (B,S,C) bf16, 64x64 tiles ----
    int i = blk - 256;                 // 0..511
    int s0 = (i & 15) * 64, c0 = ((i >> 4) & 3) * 64, b = i >> 6;
    int x = tid & 63, y0 = tid >> 6;
    #pragma unroll
    for (int y = y0; y < 64; y += 4)
      fs[y * 65 + x] = h[((size_t)(b * C_ + c0 + y)) * S_ + s0 + x];
    __syncthreads();
    #pragma unroll
    for (int y = y0; y < 64; y += 4)
      hT[((size_t)(b * S_ + s0 + y)) * C_ + c0 + x] = f2bf(fs[x * 65 + y]);
  } else {
    // ---- f32 -> bf16 converts, 8 elems per thread ----
    int base = blk - 768;              // 0..1407
    const float* src; short* dst;
    if (base < 1024)      { src = cond; dst = cond_b; }
    else if (base < 1088) { src = Wq;   dst = Wq_b;   base -= 1024; }
    else if (base < 1216) { src = Wk;   dst = Wk_b;   base -= 1088; }
    else if (base < 1344) { src = Wv;   dst = Wv_b;   base -= 1216; }
    else                  { src = Wo;   dst = Wo_b;   base -= 1344; }
    int j = base * 256 + tid;
    float4 v0 = ((const float4*)src)[j * 2];
    float4 v1 = ((const float4*)src)[j * 2 + 1];
    bf16x8 o = { f2bf(v0.x), f2bf(v0.y), f2bf(v0.z), f2bf(v0.w),
                 f2bf(v1.x), f2bf(v1.y), f2bf(v1.z), f2bf(v1.w) };
    ((bf16x8*)dst)[j] = o;
  }
}

// ==================== L2a: reduce 4 split-K partials + bias + L2-normalize ====================
__global__ __launch_bounds__(256) void k_normalize(const float* __restrict__ cp_part, const float* __restrict__ brk,
                                                   float* __restrict__ cp) {
  int row = blockIdx.x * 4 + (threadIdx.x >> 6);
  int d = threadIdx.x & 63;
  size_t off = (size_t)row * 64 + d;
  float x = brk[d];
  #pragma unroll
  for (int s = 0; s < 4; ++s) x += cp_part[(size_t)s * 262144 + off];
  float ss = x * x;
  #pragma unroll
  for (int o = 32; o; o >>= 1) ss += __shfl_xor(ss, o);
  cp[off] = x / fmaxf(sqrtf(ss), 1e-12f);
}

// ==================== L2b: centrality + top-k + mask + fallback + index compaction ====================
__global__ __launch_bounds__(512) void k_select(const float* __restrict__ cp, const int* __restrict__ mask,
                                                int* __restrict__ idxb, int* __restrict__ cnt) {
  int b = blockIdx.x, tid = threadIdx.x;
  __shared__ float part[8][64];
  __shared__ float vsum[64];
  __shared__ float sc[512];
  __shared__ int wcnt[8];
  int d = tid & 63, g = tid >> 6;
  float sacc = 0.f;
  for (int n = g * 64; n < g * 64 + 64; ++n)
    sacc += cp[((size_t)b * N_ + n) * 64 + d];
  part[g][d] = sacc;
  __syncthreads();
  if (tid < 64) {
    float v = 0.f;
    #pragma unroll
    for (int gg = 0; gg < 8; ++gg) v += part[gg][tid];
    vsum[tid] = v;
  }
  __syncthreads();
  const float* x = cp + ((size_t)b * N_ + tid) * 64;
  float dsum = 0.f, dself = 0.f;
  #pragma unroll
  for (int dd = 0; dd < 64; ++dd) {
    float xv = x[dd];
    dsum += xv * vsum[dd];
    dself += xv * xv;
  }
  sc[tid] = dsum - dself;
  __syncthreads();
  float v = sc[tid];
  int rank = 0;
  for (int j = 0; j < N_; ++j) {
    float u = sc[j];
    rank += (u > v) || (u == v && j < tid);
  }
  int sel = (rank < KSEL_) && (mask[b * N_ + tid] != 0);
  unsigned long long bal = __ballot(sel);
  if ((tid & 63) == 0) wcnt[g] = __popcll(bal);
  __syncthreads();
  int off2 = 0, total = 0;
  #pragma unroll
  for (int i = 0; i < 8; ++i) { int c = wcnt[i]; total += c; if (i < g) off2 += c; }
  int pos = off2 + __popcll(bal & ((1ull << (tid & 63)) - 1ull));
  if (sel) idxb[b * N_ + pos] = tid;
  if (total == 0 && rank == 0) idxb[b * N_] = tid;
  if (tid == 0) cnt[b] = (total == 0) ? 1 : total;
}

// ==================== MFMA GEMM body: (WM*32)x128 tile, BK=32, 3-buf counted-vmcnt pipeline ====================
template<int MODE, int GA, int GB, int WM>
__device__ __forceinline__ void gemm_body(const short* __restrict__ A, const short* __restrict__ W,
                                          const float* __restrict__ bias, void* __restrict__ Cout,
                                          short* As, short* Bs, size_t bm, size_t bn, int Kd, int Nout,
                                          const int* __restrict__ gidx, int cntv) {
  constexpr int BMv = WM * 32;
  constexpr int NIA = BMv / 64;
  constexpr int OPS = NIA + 2;
  int tid = threadIdx.x;
  int lane = tid & 63, wid = tid >> 6;
  int wr = wid >> 1, wc = wid & 1;
  f32x4 acc[WM][4] = {};
  int srow = lane >> 2;
  int schunk = lane & 3;
  int steps = Kd >> 5;

  int rowA[NIA ? NIA : 1], rowB[2];
  #pragma unroll
  for (int i = 0; i < NIA; ++i) {
    int rt = wid * (WM * 8) + i * 16 + srow;
    rowA[i] = GA ? (((int)bm + rt < cntv) ? gidx[bm + rt] : 0) : (int)(bm + rt);
  }
  #pragma unroll
  for (int i = 0; i < 2; ++i) {
    int rt = wid * 32 + i * 16 + srow;
    rowB[i] = GB ? (((int)bn + rt < cntv) ? gidx[bn + rt] : 0) : (int)(bn + rt);
  }

  #define STAGE_G(t, buf)                                                                              \
    {                                                                                                  \
      int k0s = (t) * 32;                                                                              \
      _Pragma("unroll")                                                                                \
      for (int i = 0; i < NIA; ++i) {                                                                  \
        int rt = wid * (WM * 8) + i * 16 + srow;                                                       \
        int sc_ = (schunk ^ ((rt >> 1) & 3)) * 8;                                                      \
        const short* ga = A + (size_t)rowA[i] * Kd + k0s + sc_;                                        \
        __builtin_amdgcn_global_load_lds((const __attribute__((address_space(1))) void*)ga,            \
            (__attribute__((address_space(3))) void*)(As + (buf) * (BMv * 32) +                        \
                                                     (wid * (WM * 8) + i * 16) * 32),                  \
            16, 0, 0);                                                                                 \
      }                                                                                                \
      _Pragma("unroll")                                                                                \
      for (int i = 0; i < 2; ++i) {                                                                    \
        int rt = wid * 32 + i * 16 + srow;                                                             \
        int sc_ = (schunk ^ ((rt >> 1) & 3)) * 8;                                                      \
        const short* gb = W + (size_t)rowB[i] * Kd + k0s + sc_;                                        \
        __builtin_amdgcn_global_load_lds((const __attribute__((address_space(1))) void*)gb,            \
            (__attribute__((address_space(3))) void*)(Bs + (buf) * 4096 + (wid * 32 + i * 16) * 32),   \
            16, 0, 0);                                                                                 \
      }                                                                                                \
    }

  STAGE_G(0, 0);
  STAGE_G(1, 1);

  int cur = 0;
  for (int t = 0; t < steps; ++t) {
    if (t == steps - 1)
      asm volatile("s_waitcnt vmcnt(0)" ::: "memory");
    else
      asm volatile("s_waitcnt vmcnt(%0)" :: "n"(OPS) : "memory");
    __syncthreads();
    if (t + 2 < steps) {
      int nb = cur + 2; if (nb >= 3) nb -= 3;
      STAGE_G(t + 2, nb);
    }
    const short* Ac = As + cur * (BMv * 32);
    const short* Bc = Bs + cur * 4096;
    bf16x8 a[WM], b[4];
    #pragma unroll
    for (int m = 0; m < WM; ++m) {
      int rt = wr * (WM * 16) + m * 16 + (lane & 15);
      a[m] = *(const bf16x8*)(Ac + rt * 32 + (((lane >> 4) ^ ((rt >> 1) & 3)) * 8));
    }
    #pragma unroll
    for (int n = 0; n < 4; ++n) {
      int rt = wc * 64 + n * 16 + (lane & 15);
      b[n] = *(const bf16x8*)(Bc + rt * 32 + (((lane >> 4) ^ ((rt >> 1) & 3)) * 8));
    }
    #pragma unroll
    for (int m = 0; m < WM; ++m)
      #pragma unroll
      for (int n = 0; n < 4; ++n)
        acc[m][n] = __builtin_amdgcn_mfma_f32_16x16x32_bf16(a[m], b[n], acc[m][n], 0, 0, 0);
    cur = (cur == 2) ? 0 : cur + 1;
  }
  #undef STAGE_G

  int c0 = lane & 15, r0q = lane >> 4;
  #pragma unroll
  for (int n = 0; n < 4; ++n) {
    size_t col = bn + wc * 64 + n * 16 + c0;
    #pragma unroll
    for (int m = 0; m < WM; ++m) {
      #pragma unroll
      for (int j = 0; j < 4; ++j) {
        size_t row = bm + wr * (WM * 16) + m * 16 + r0q * 4 + j;
        if (MODE == 0) {
          ((short*)Cout)[row * Nout + col] = f2bf(acc[m][n][j] + bias[col]);
        } else if (MODE == 1) {
          ((float*)Cout)[((col >> 10) * C_ + row) * S_ + (col & (S_ - 1))] = acc[m][n][j] + bias[row];
        } else {
          ((short*)Cout)[row * Nout + col] = f2bf(acc[m][n][j] + bias[row]);
        }
      }
    }
  }
}

// ==================== L3: compacted K-proj + V^T-proj (WM=2, balanced) + q-proj (WM=4) ====================
__global__ __launch_bounds__(256) void k_fused_proj(const short* __restrict__ hT, const short* __restrict__ cond_b,
                                                    const short* __restrict__ Wq_b, const short* __restrict__ Wk_b,
                                                    const short* __restrict__ Wv_b,
                                                    const float* __restrict__ bq, const float* __restrict__ bk,
                                                    const float* __restrict__ bv,
                                                    short* __restrict__ qb, short* __restrict__ Kc,
                                                    short* __restrict__ Vtc,
                                                    const int* __restrict__ idxb, const int* __restrict__ cnt) {
  __shared__ short smem[24576];
  int blk = blockIdx.x;
  if (blk < 192) {
    int b = blk / 24, j = blk % 24;
    int mt = j >> 2, ntile = j & 3;
    int cv = cnt[b], padded = (cv + 63) & ~63;
    if (mt * 64 >= padded) return;
    gemm_body<0, 1, 0, 2>(cond_b + (size_t)b * N_ * KV_, Wk_b, bk, Kc + (size_t)b * N_ * KV_,
                          smem, smem + 12288, (size_t)mt * 64, (size_t)ntile * 128, KV_, KV_,
                          idxb + b * N_, cv);
  } else if (blk < 384) {
    int i = blk - 192, b = i / 24, j = i % 24;
    int ntc = j >> 3, mtd = j & 7;
    int cv = cnt[b], padded = (cv + 63) & ~63;
    if (ntc * 128 >= padded) return;
    gemm_body<3, 0, 1, 2>(Wv_b, cond_b + (size_t)b * N_ * KV_, bv, Vtc + (size_t)b * 512 * N_,
                          smem, smem + 12288, (size_t)mtd * 64, (size_t)ntc * 128, KV_, N_,
                          idxb + b * N_, cv);
  } else {
    int i = blk - 384;
    gemm_body<0, 0, 0, 4>(hT, Wq_b, bq, qb, smem, smem + 12288,
                          (size_t)(i & 63) * 128, (size_t)(i >> 6) * 128, C_, KV_, nullptr, 0);
  }
}

// ==================== staging helper (layout: LDS[r][c] = G[r][c ^ (r&7)], 128-B rows) ====================
__device__ __forceinline__ void stage_tile64_w8(const short* gRowBase, int gStride, short* ldsBase, int wid, int lane) {
  int sub = lane >> 3;
  int colE = ((lane & 7) ^ sub) * 8;
  int r = wid * 8 + sub;
  const short* gp = gRowBase + (size_t)r * gStride + colE;
  __builtin_amdgcn_global_load_lds((const __attribute__((address_space(1))) void*)gp,
                                   (__attribute__((address_space(3))) void*)(ldsBase + wid * 512),
                                   16, 0, 0);
}

// ==================== L4: MFMA flash attention, 128 q/block, 8 waves, Q direct-to-reg ====================
#define QK2L 0.18033688f  // 0.125 * log2(e)
__global__ __launch_bounds__(512) void k_attn_mfma(const short* __restrict__ qb, const short* __restrict__ Kc,
                                                   const short* __restrict__ Vtc, const int* __restrict__ cnt,
                                                   short* __restrict__ attn_b) {
  __shared__ short Ps[8192];
  __shared__ short Ks[2][4096];
  __shared__ short Vs[2][4096];
  int g = blockIdx.x;
  int xcd = g & 7, li = g >> 3;
  int bh = xcd * 8 + (li >> 3);
  int qt = li & 7;
  int b = bh >> 3, h = bh & 7;
  int tid = threadIdx.x, lane = tid & 63, wid = tid >> 6;
  int hi = lane >> 4, q = lane & 15;
  int swz = (lane & 7) << 3;
  int s0 = qt * 128;
  int cntv = cnt[b];
  int nt = (cntv + 63) >> 6;
  const short* Qg = qb + ((size_t)(b * S_ + s0) * KV_ + h * DH_);
  const short* Kg = Kc + ((size_t)(b * N_) * KV_ + h * DH_);
  const short* Vg = Vtc + ((size_t)((b * NH_ + h) * DH_) * N_);

  bf16x8 qf0 = *(const bf16x8*)(Qg + (size_t)(wid * 16 + q) * KV_ + hi * 8);
  bf16x8 qf1 = *(const bf16x8*)(Qg + (size_t)(wid * 16 + q) * KV_ + 32 + hi * 8);

  stage_tile64_w8(Kg, KV_, Ks[0], wid, lane);
  stage_tile64_w8(Vg, N_, Vs[0], wid, lane);
  asm volatile("s_waitcnt vmcnt(0)" ::: "memory");
  __syncthreads();

  float m = -1e30f, l = 0.f;
  f32x4 o[4] = {};

  for (int t = 0; t < nt; ++t) {
    int cur = t & 1;
    const short* Kcur = Ks[cur];
    const short* Vcur = Vs[cur];
    if (t + 1 < nt) {
      stage_tile64_w8(Kg + (size_t)(t + 1) * 64 * KV_, KV_, Ks[cur ^ 1], wid, lane);
      stage_tile64_w8(Vg + (t + 1) * 64, N_, Vs[cur ^ 1], wid, lane);
    }
    f32x4 pv[4];
    __builtin_amdgcn_s_setprio(1);
    #pragma unroll
    for (int kf = 0; kf < 4; ++kf) {
      bf16x8 k0 = *(const bf16x8*)&Kcur[(kf * 16 + q) * 64 + ((hi * 8) ^ swz)];
      bf16x8 k1 = *(const bf16x8*)&Kcur[(kf * 16 + q) * 64 + ((32 + hi * 8) ^ swz)];
      f32x4 z = {0.f, 0.f, 0.f, 0.f};
      pv[kf] = __builtin_amdgcn_mfma_f32_16x16x32_bf16(k0, qf0, z, 0, 0, 0);
      pv[kf] = __builtin_amdgcn_mfma_f32_16x16x32_bf16(k1, qf1, pv[kf], 0, 0, 0);
    }
    __builtin_amdgcn_s_setprio(0);
    float sv[16];
    int kbase = t * 64 + hi * 4;
    #pragma unroll
    for (int kf = 0; kf < 4; ++kf) {
      #pragma unroll
      for (int r = 0; r < 4; ++r)
        sv[kf * 4 + r] = (kbase + kf * 16 + r < cntv) ? pv[kf][r] * QK2L : -1e30f;
    }
    float tmax = sv[0];
    #pragma unroll
    for (int i = 1; i < 16; ++i) tmax = fmaxf(tmax, sv[i]);
    tmax = fmaxf(tmax, __shfl_xor(tmax, 16));
    tmax = fmaxf(tmax, __shfl_xor(tmax, 32));
    float mnew = fmaxf(m, tmax);
    float scale = exp2f(m - mnew);
    float psum = 0.f;
    #pragma unroll
    for (int i = 0; i < 16; ++i) { sv[i] = exp2f(sv[i] - mnew); psum += sv[i]; }
    psum += __shfl_xor(psum, 16);
    psum += __shfl_xor(psum, 32);
    l = l * scale + psum;
    m = mnew;
    #pragma unroll
    for (int df = 0; df < 4; ++df) {
      o[df][0] *= scale; o[df][1] *= scale; o[df][2] *= scale; o[df][3] *= scale;
    }
    int pbase = wid * 1024 + q * 64;
    #pragma unroll
    for (int kf = 0; kf < 4; ++kf) {
      short4v pk = { f2bf(sv[kf * 4 + 0]), f2bf(sv[kf * 4 + 1]), f2bf(sv[kf * 4 + 2]), f2bf(sv[kf * 4 + 3]) };
      *(short4v*)&Ps[pbase + ((kf * 16 + hi * 4) ^ swz)] = pk;
    }
    __builtin_amdgcn_s_setprio(1);
    #pragma unroll
    for (int ks = 0; ks < 2; ++ks) {
      bf16x8 pb = *(const bf16x8*)&Ps[pbase + ((ks * 32 + hi * 8) ^ swz)];
      #pragma unroll
      for (int df = 0; df < 4; ++df) {
        bf16x8 vf = *(const bf16x8*)&Vcur[(df * 16 + q) * 64 + ((ks * 32 + hi * 8) ^ swz)];
        o[df] = __builtin_amdgcn_mfma_f32_16x16x32_bf16(vf, pb, o[df], 0, 0, 0);
      }
    }
    __builtin_amdgcn_s_setprio(0);
    if (t + 1 < nt) {
      asm volatile("s_waitcnt vmcnt(0)" ::: "memory");
      __syncthreads();
    }
  }
  float inv = 1.0f / l;
  short* op = attn_b + ((size_t)(b * S_ + s0 + wid * 16 + q) * KV_ + h * DH_);
  #pragma unroll
  for (int df = 0; df < 4; ++df) {
    short4v ov = { f2bf(o[df][0] * inv), f2bf(o[df][1] * inv), f2bf(o[df][2] * inv), f2bf(o[df][3] * inv) };
    *(short4v*)&op[df * 16 + hi * 4] = ov;
  }
}

// ==================== L5: output projection, BM=64, XCD-grouped 1-D grid (256 blocks) ====================
__global__ __launch_bounds__(256) void k_outproj(const short* __restrict__ Wo_b, const short* __restrict__ attn_b,
                                                 const float* __restrict__ bo, float* __restrict__ out) {
  __shared__ short smem[18432];
  int bid = blockIdx.x;
  int xcd = bid & 7, j = bid >> 3;
  int p = ((j >> 2) << 3) | xcd;
  int i = j & 3;
  gemm_body<1, 0, 0, 2>(Wo_b, attn_b, bo, out, smem, smem + 6144,
                        (size_t)i * 64, (size_t)p * 128, KV_, B_ * S_, nullptr, 0);
}

extern "C" void kernel_launch(void* const* d_in, const int* in_sizes, int n_in,
                              void* d_out, int out_size, void* d_ws, size_t ws_size,
                              hipStream_t stream) {
  const float* h         = (const float*)d_in[0];
  const float* cond      = (const float*)d_in[1];
  const int*   cond_mask = (const int*)d_in[2];
  const float* Wq = (const float*)d_in[3];
  const float* bq = (const float*)d_in[4];
  const float* Wk = (const float*)d_in[5];
  const float* bk = (const float*)d_in[6];
  const float* Wv = (const float*)d_in[7];
  const float* bv = (const float*)d_in[8];
  const float* Wrk = (const float*)d_in[11];
  const float* brk = (const float*)d_in[12];
  const float* Wo  = (const float*)d_in[13];
  const float* bo  = (const float*)d_in[14];
  float* out = (float*)d_out;

  char* w = (char*)d_ws;
  short* qb      = (short*)(w + 0);          // 8 MB
  short* Kc      = (short*)(w + 8388608);    // 4 MB
  short* Vtc     = (short*)(w + 12582912);   // 4 MB
  short* attn_b  = (short*)(w + 16777216);   // 8 MB
  short* hT      = (short*)(w + 25165824);   // 4 MB
  short* cond_b  = (short*)(w + 29360128);   // 4 MB
  float* cp_part = (float*)(w + 33554432);   // 4 MB (4 split-K slices)
  float* cp      = (float*)(w + 37748736);   // 1 MB
  int*   idxb    = (int*)  (w + 38797312);   // 16 KB
  int*   cnt     = (int*)  (w + 38813696);   // 64 B
  short* Wq_b    = (short*)(w + 38813760);   // 256 KB
  short* Wk_b    = (short*)(w + 39075904);   // 512 KB
  short* Wv_b    = (short*)(w + 39600192);   // 512 KB
  short* Wo_b    = (short*)(w + 40124480);   // 256 KB

  // L1: rel-proj (split-K x4, straggler-first) + h-transpose 64x64 + converts
  k_prep<<<2176, 256, 0, stream>>>(cond, Wq, Wk, Wv, Wo, h, Wrk,
                                   cond_b, Wq_b, Wk_b, Wv_b, Wo_b, hT, cp_part);
  // L2a: normalize (parallel, 1 wave/row)
  k_normalize<<<1024, 256, 0, stream>>>(cp_part, brk, cp);
  // L2b: centrality + top-k + compaction
  k_select<<<8, 512, 0, stream>>>(cp, cond_mask, idxb, cnt);
  // L3: balanced K/V^T-proj (WM=2) + q-proj (WM=4), 640 blocks all-resident
  k_fused_proj<<<640, 256, 0, stream>>>(hT, cond_b, Wq_b, Wk_b, Wv_b, bq, bk, bv,
                                        qb, Kc, Vtc, idxb, cnt);
  // L4: attention over compacted keys (128 q/block, XCD-grouped, Q direct-to-reg)
  k_attn_mfma<<<512, 512, 0, stream>>>(qb, Kc, Vtc, cnt, attn_b);
  // L5: output projection -> (B,C,S), 256 blocks XCD-grouped
  k_outproj<<<256, 256, 0, stream>>>(Wo_b, attn_b, bo, out);
}